// Round 6
// baseline (606.460 us; speedup 1.0000x reference)
//
#include <hip/hip_runtime.h>
#include <hip/hip_bf16.h>
#include <math.h>

// ---------- dims ----------
#define BATCH 17
#define T_EX 16
#define H0 383
#define W0 287
#define C1 64
#define H1 95
#define W1 71
#define H1P 47
#define W1P 35
#define C2 192
#define H2P 23
#define W2P 17
#define C3 384
#define C45 256
#define H5P 11
#define W5P 8
#define DD 256
#define MM 88
#define TM 1408

#define HP1 389
#define WP1 292

typedef unsigned short ushort_t;
typedef __attribute__((ext_vector_type(8))) short short8;
typedef __attribute__((ext_vector_type(4))) float f32x4;

__device__ __forceinline__ float lrelu(float v) { return v > 0.f ? v : 0.01f * v; }

__device__ __forceinline__ ushort_t f2bf(float f) {
    unsigned int u = __float_as_uint(f);
    unsigned int r = (u + 0x7fffu + ((u >> 16) & 1u)) >> 16;
    return (ushort_t)r;
}
__device__ __forceinline__ float b2f(ushort_t b) {
    return __uint_as_float(((unsigned int)b) << 16);
}
__device__ __forceinline__ short8 ld16(const ushort_t* p) { return *(const short8*)p; }
__device__ __forceinline__ short8 ld2x8(const ushort_t* p) {
    union { uint2 u[2]; short8 s; } uu;
    uu.u[0] = *(const uint2*)p;
    uu.u[1] = *(const uint2*)(p + 4);
    return uu.s;
}

// ---------- zero fill ----------
__global__ void zfill_k(float4* __restrict__ p, int n4) {
    int idx = blockIdx.x * 256 + threadIdx.x;
    if (idx < n4) p[idx] = (float4){0.f, 0.f, 0.f, 0.f};
}

// ---------- conv1 input prep: fp32 NCHW -> bf16 NHWC padded (C=4, pad 2) ----------
__global__ void prep1_k(const float* __restrict__ search, const float* __restrict__ exemp,
                        ushort_t* __restrict__ out) {
    int idx = blockIdx.x * 256 + threadIdx.x;
    if (idx >= BATCH * H0 * W0) return;
    int ix = idx % W0; int t = idx / W0;
    int iy = t % H0; int b = t / H0;
    const float* src = (b == 0) ? search : exemp + (size_t)(b - 1) * 3 * H0 * W0;
    const int hw = H0 * W0;
    float v0 = src[iy * W0 + ix];
    float v1 = src[hw + iy * W0 + ix];
    float v2 = src[2 * hw + iy * W0 + ix];
    ushort4 o;
    o.x = f2bf(v0); o.y = f2bf(v1); o.z = f2bf(v2); o.w = 0;
    *(ushort4*)&out[(((size_t)b * HP1 + iy + 2) * WP1 + ix + 2) * 4] = o;
}

// ---------- conv weight prep: OIHW fp32 -> bf16 MFMA tiles, K-order (ky,kx,ic) ----------
__global__ void wprep_k(const float* __restrict__ w, ushort_t* __restrict__ out,
                        int KH, int KWl, int KWr, int CINl, int CINr,
                        int NKS, int nch, int OCr) {
    int idx = blockIdx.x * 256 + threadIdx.x;
    if (idx >= nch) return;
    int c = idx & 255;
    int rest = idx >> 8;
    int ks = rest % NKS;
    int ocb = rest / NKS;
    int k8 = c >> 6, m = c & 63;
    int oc = ocb * 64 + m;
    int KWC = KWl * CINl;
    ushort_t* o = out + (size_t)idx * 8;
#pragma unroll
    for (int j = 0; j < 8; ++j) {
        int kg = ks * 32 + k8 * 8 + j;
        int ky = kg / KWC; int rem = kg - ky * KWC;
        int kx = rem / CINl; int ic = rem - kx * CINl;
        float v = 0.f;
        if (oc < OCr && ky < KH && kx < KWr && ic < CINr)
            v = w[(((size_t)oc * CINr + ic) * KH + ky) * KWr + kx];
        o[j] = f2bf(v);
    }
}

// ---------- fused gemm weight prep (ws1 | ws2 | wcd), tiled layout ----------
__global__ void wprep_gemm_k(const float* __restrict__ ws1, const float* __restrict__ ws2,
                             const float* __restrict__ wcd, ushort_t* __restrict__ WS1T,
                             ushort_t* __restrict__ WS2T, ushort_t* __restrict__ WCDT) {
    int idx = blockIdx.x * 256 + threadIdx.x;
    const float* src; ushort_t* dst; int NKS, mode = 0, sa = 1, sk = 0, base;
    if (idx < 16384)       { src = ws1; dst = WS1T; NKS = 8;  sk = 512; base = idx; }
    else if (idx < 32768)  { src = ws2; dst = WS2T; NKS = 16; sk = 256; base = idx - 16384; }
    else if (idx < 57344)  { src = wcd; dst = WCDT; NKS = 24; mode = 1; base = idx - 32768; }
    else return;
    int c = base & 255;
    int rest = base >> 8;
    int ks = rest % NKS;
    int ocb = rest / NKS;
    int k8 = c >> 6, m = c & 63;
    int oc = ocb * 64 + m;
    ushort_t* o = dst + (size_t)base * 8;
#pragma unroll
    for (int j = 0; j < 8; ++j) {
        int kg = ks * 32 + k8 * 8 + j;
        float v;
        if (mode == 0) v = src[(size_t)oc * sa + (size_t)kg * sk];
        else           v = src[(size_t)oc * 768 + (kg & 255) * 3 + (kg >> 8)];
        o[j] = f2bf(v);
    }
}

// ====================================================================
// bf16 MFMA implicit-GEMM conv, v12 = v11 + COALESCED px-major staging.
//  Theory (r0-r5): all prior variants staged B with lane=pixel, pixel
//  stride = C*2B >= 128B -> each 64-lane load touches 64 cache lines
//  -> ~64 L1/TA request-cycles per instruction; B-staging alone ~27us
//  of L1 port time for conv2. Never varied across r0-r5 -> the
//  invariant ~54-85us wall.
//  Fix: instruction i covers pixel OCTET i: lane L loads px=i*8+L/8,
//  k-group g8=L&7 -> 8-lane groups read contiguous 128B -> 16 lines
//  per instruction (4x fewer). Requires lane->LDS transpose, so
//  global->reg->ds_write (T14: loads issued before compute, writes
//  after -> HBM latency hidden under MFMAs). LDS layout, fragment
//  reads, K-order, accumulation order: IDENTICAL to v11 -> bitwise
//  same results.
//  - block = 1 wave = NOC oc x 64 px; no barriers in main loop.
//  - A direct from global (pre-tiled, L2-resident), ping-pong regs.
// ====================================================================
template <int NOC, bool LD16, int STRIDE>
__global__ __launch_bounds__(64, 2) void conv_mfma12(
    const ushort_t* __restrict__ inp, const ushort_t* __restrict__ wt,
    const float* __restrict__ bias, ushort_t* __restrict__ out,
    int Hp, int Wp, int C, int Wout, int HW, int Ntot, int NKS2, int KWl,
    int OHp, int OWp, int OPAD, int COUT) {
    constexpr int AM = NOC / 16;      // oc fragments per wave
    constexpr int SUB = 64 / NOC;     // sub-tiles per 64-oc weight tile
    const int lane = threadIdx.x;
    const int quad = lane >> 4, l16 = lane & 15;
    const int g8 = lane & 7, po = lane >> 3;   // staging role: k-group, px-in-octet
    const int n_blk = blockIdx.x * 64;
    const int ocb = blockIdx.y;

    __shared__ ushort_t Bs[2][4096];  // [buf][k8:8][px:64][8] = 8 KB/buf
    __shared__ int offs[432];

    const int KWC = KWl * C;
    for (int g = lane; g < NKS2 * 8; g += 64) {
        int kg = g * 8;
        int ky = kg / KWC; int rem = kg - ky * KWC;
        int kx = rem / C; int c8 = rem - kx * C;
        offs[g] = (ky * Wp + kx) * C + c8;
    }
    __syncthreads();   // once, at init

    // px-major staging pointers: inst i covers px octet i; this lane's
    // pixel for inst i is n_blk + i*8 + po (clamped).
    const ushort_t* bp[8];
#pragma unroll
    for (int i = 0; i < 8; ++i) {
        int n = n_blk + i * 8 + po; if (n >= Ntot) n = Ntot - 1;
        int b = n / HW, p = n - b * HW;
        int oy = p / Wout, ox = p - oy * Wout;
        bp[i] = inp + (size_t)b * Hp * Wp * C +
                (size_t)(oy * STRIDE * Wp + ox * STRIDE) * C;
    }

    // A: pre-tiled [oc64][ks32][k8:4][m:64][8]
    const ushort_t* wA = wt + (size_t)(ocb / SUB) * (size_t)NKS2 * 4096 +
                         quad * 512 + (size_t)((ocb % SUB) * NOC + l16) * 8;

    f32x4 acc[AM][4];
#pragma unroll
    for (int am = 0; am < AM; ++am)
#pragma unroll
        for (int cn = 0; cn < 4; ++cn) acc[am][cn] = (f32x4){0.f, 0.f, 0.f, 0.f};

    short8 rb[8];
    auto ldBr = [&](int ks2) {
        const int mo = offs[ks2 * 8 + g8];
#pragma unroll
        for (int i = 0; i < 8; ++i) {
            if constexpr (LD16) rb[i] = ld16(bp[i] + mo);
            else                rb[i] = ld2x8(bp[i] + mo);
        }
    };
    auto wrB = [&](int buf) {
        // element (kg=g8, px=i*8+po) at kg*512 + px*8  (same layout as v11)
#pragma unroll
        for (int i = 0; i < 8; ++i)
            *(short8*)&Bs[buf][g8 * 512 + po * 8 + i * 64] = rb[i];
    };
    auto ldA = [&](short8 (&A)[2][AM], int ks2) {
        const ushort_t* p = wA + (size_t)ks2 * 4096;
#pragma unroll
        for (int h = 0; h < 2; ++h)
#pragma unroll
            for (int am = 0; am < AM; ++am)
                A[h][am] = ld16(p + h * 2048 + am * 128);
    };
    auto compute = [&](const short8 (&A)[2][AM], const ushort_t* Bb) {
#pragma unroll
        for (int h = 0; h < 2; ++h) {
            short8 Bf[4];
#pragma unroll
            for (int cn = 0; cn < 4; ++cn)
                Bf[cn] = *(const short8*)&Bb[(h * 4 + quad) * 512 + (cn * 16 + l16) * 8];
#pragma unroll
            for (int cn = 0; cn < 4; ++cn)
#pragma unroll
                for (int am = 0; am < AM; ++am)
                    acc[am][cn] = __builtin_amdgcn_mfma_f32_16x16x32_bf16(A[h][am], Bf[cn], acc[am][cn], 0, 0, 0);
        }
    };

    short8 Aa[2][AM], Ab[2][AM];
    // prologue: step 0 into buf 0
    ldBr(0); wrB(0);
    ldA(Aa, 0);

    int ks2 = 0;
    for (;;) {
        bool more = ks2 + 1 < NKS2;
        if (more) { ldBr(ks2 + 1); ldA(Ab, ks2 + 1); }   // issue early (T14)
        asm volatile("s_waitcnt lgkmcnt(0)" ::: "memory");
        compute(Aa, &Bs[0][0]);
        if (!more) break;
        wrB(1);                                          // write late
        ks2++;
        more = ks2 + 1 < NKS2;
        if (more) { ldBr(ks2 + 1); ldA(Aa, ks2 + 1); }
        asm volatile("s_waitcnt lgkmcnt(0)" ::: "memory");
        compute(Ab, &Bs[1][0]);
        if (!more) break;
        wrB(0);
        ks2++;
    }

    const int ocB = ocb * NOC + quad * 4;
#pragma unroll
    for (int cn = 0; cn < 4; ++cn) {
        int n = n_blk + cn * 16 + l16;
        if (n < Ntot) {
            int bb = n / HW; int pix = n - bb * HW;
            int y = pix / Wout, x = pix - y * Wout;
            size_t base = (((size_t)bb * OHp + y + OPAD) * OWp + x + OPAD) * COUT;
#pragma unroll
            for (int am = 0; am < AM; ++am) {
                const int oc = ocB + am * 16;
                ushort4 o;
                o.x = f2bf(fmaxf(acc[am][cn][0] + bias[oc], 0.f));
                o.y = f2bf(fmaxf(acc[am][cn][1] + bias[oc + 1], 0.f));
                o.z = f2bf(fmaxf(acc[am][cn][2] + bias[oc + 2], 0.f));
                o.w = f2bf(fmaxf(acc[am][cn][3] + bias[oc + 3], 0.f));
                *(ushort4*)&out[base + oc] = o;
            }
        }
    }
}

// ====================================================================
// Generic bf16 MFMA GEMM: A direct from global (tiled), B LDS dbuf.
// ====================================================================
template <int MODE, bool HASBIAS, bool SC1>
__global__ __launch_bounds__(256) void gemm_mfma3(
    const ushort_t* __restrict__ Bsrc, const ushort_t* __restrict__ wt,
    const float* __restrict__ bias, float* __restrict__ out,
    int RS, int N, int NKS, int sn, int sc) {
    const int tid = threadIdx.x;
    const int wv = tid >> 6, lane = tid & 63;
    const int quad = lane >> 4, l16 = lane & 15;
    const int n_blk = blockIdx.x * 64;
    const int ocb = blockIdx.y;

    __shared__ ushort_t Bs[2][2048];

    int n_g = n_blk + lane;
    int n_gc = n_g < N ? n_g : N - 1;
    int row = (MODE == 1) ? (1 + (n_gc & 15)) * MM + (n_gc >> 4) : n_gc;
    const size_t base0 = (size_t)row * RS;

    f32x4 acc[4];
#pragma unroll
    for (int cn = 0; cn < 4; ++cn) acc[cn] = (f32x4){0.f, 0.f, 0.f, 0.f};

    const ushort_t* wblk = wt + (size_t)ocb * NKS * 2048;
    const int afrag = (quad * 64 + wv * 16 + l16) * 8;

    short8 a0 = ld16(wblk + afrag);
    *(short8*)&Bs[0][tid * 8] = ld16(Bsrc + base0 + wv * 8);
    __syncthreads();

    for (int ks = 0; ks < NKS; ++ks) {
        const int cur = ks & 1, nxt = cur ^ 1;
        short8 a1, bn;
        const bool more = (ks + 1 < NKS);
        if (more) {
            a1 = ld16(wblk + (ks + 1) * 2048 + afrag);
            bn = ld16(Bsrc + base0 + (ks + 1) * 32 + wv * 8);
        }
#pragma unroll
        for (int cn = 0; cn < 4; ++cn) {
            const short8 bfr = *(const short8*)&Bs[cur][(quad * 64 + cn * 16 + l16) * 8];
            acc[cn] = __builtin_amdgcn_mfma_f32_16x16x32_bf16(a0, bfr, acc[cn], 0, 0, 0);
        }
        if (more) *(short8*)&Bs[nxt][tid * 8] = bn;
        a0 = a1;
        __syncthreads();
    }

    const int oc0 = ocb * 64 + wv * 16 + quad * 4;
    float bb[4] = {0.f, 0.f, 0.f, 0.f};
    if (HASBIAS) { bb[0] = bias[oc0]; bb[1] = bias[oc0+1]; bb[2] = bias[oc0+2]; bb[3] = bias[oc0+3]; }
#pragma unroll
    for (int cn = 0; cn < 4; ++cn) {
        int n = n_blk + cn * 16 + l16;
        if (n < N) {
            if (SC1) {
                float4 o;
                o.x = acc[cn][0] + bb[0]; o.y = acc[cn][1] + bb[1];
                o.z = acc[cn][2] + bb[2]; o.w = acc[cn][3] + bb[3];
                *(float4*)&out[(size_t)n * sn + oc0] = o;
            } else {
#pragma unroll
                for (int reg = 0; reg < 4; ++reg)
                    out[(size_t)n * sn + (size_t)(oc0 + reg) * sc] = acc[cn][reg] + bb[reg];
            }
        }
    }
}

// ---------- maxpool k3 s2 VALID, NHWC bf16 ----------
__global__ void pool_nhwc(const ushort_t* __restrict__ in, ushort_t* __restrict__ out,
                          int C, int Hin, int Win, int Hout, int Wout,
                          int OHp, int OWp, int OPAD) {
    int total = BATCH * C * Hout * Wout;
    int idx = blockIdx.x * 256 + threadIdx.x;
    if (idx >= total) return;
    int c = idx % C; int r = idx / C;
    int x = r % Wout; r /= Wout;
    int y = r % Hout; int b = r / Hout;
    const int rs = Win * C;
    const ushort_t* p = in + (((size_t)b * Hin + 2 * y) * Win + 2 * x) * C + c;
    float m = b2f(p[0]);
    m = fmaxf(m, b2f(p[C])); m = fmaxf(m, b2f(p[2 * C]));
    m = fmaxf(m, b2f(p[rs])); m = fmaxf(m, b2f(p[rs + C])); m = fmaxf(m, b2f(p[rs + 2 * C]));
    m = fmaxf(m, b2f(p[2 * rs])); m = fmaxf(m, b2f(p[2 * rs + C])); m = fmaxf(m, b2f(p[2 * rs + 2 * C]));
    out[(((size_t)b * OHp + y + OPAD) * OWp + x + OPAD) * C + c] = f2bf(m);
}

// ---------- pool5: NHWC bf16 -> P fp32 [b][m][d] + PB bf16 + XfPad ----------
__global__ void pool5_k(const ushort_t* __restrict__ in, float* __restrict__ P,
                        ushort_t* __restrict__ PB, ushort_t* __restrict__ XfPad) {
    int total = BATCH * 256 * MM;
    int idx = blockIdx.x * 256 + threadIdx.x;
    if (idx >= total) return;
    int c = idx % 256; int r = idx / 256;
    int x = r % W5P; r /= W5P;
    int y = r % H5P; int b = r / H5P;
    const int rs = W2P * 256;
    const ushort_t* p = in + (((size_t)b * H2P + 2 * y) * W2P + 2 * x) * 256 + c;
    float m = b2f(p[0]);
    m = fmaxf(m, b2f(p[256])); m = fmaxf(m, b2f(p[512]));
    m = fmaxf(m, b2f(p[rs])); m = fmaxf(m, b2f(p[rs + 256])); m = fmaxf(m, b2f(p[rs + 512]));
    m = fmaxf(m, b2f(p[2 * rs])); m = fmaxf(m, b2f(p[2 * rs + 256])); m = fmaxf(m, b2f(p[2 * rs + 512]));
    int mm = y * W5P + x;
    size_t o = ((size_t)b * MM + mm) * 256 + c;
    P[o] = m;
    ushort_t mb = f2bf(m);
    PB[o] = mb;
    if (b == 0) XfPad[(size_t)(mm + 1) * 256 + c] = mb;
}

// ---------- xhat with in-block vmax (fused) ----------
__global__ void xhat2_k(const float* __restrict__ xc, const float* __restrict__ wt,
                        const float* __restrict__ bt, float* __restrict__ xhat) {
    __shared__ float lv[256];
    {
        int j = threadIdx.x;
        const float* xr = xc + (size_t)j * MM;
        float mx = xr[0];
        for (int k = 1; k < MM; ++k) mx = fmaxf(mx, xr[k]);
        lv[j] = mx;
    }
    __syncthreads();
    int idx = blockIdx.x * 256 + threadIdx.x;
    if (idx >= DD * MM) return;
    int k = idx % MM, o = idx / MM;
    float acc = bt[o];
    for (int i = 0; i < 256; ++i) acc = fmaf(lv[i], wt[(i * 256 + o) * MM + k], acc);
    xhat[idx] = acc;
}

// ---------- fused s1+h1 ----------
__global__ void sh1_k(const float* __restrict__ Y1, const float* __restrict__ bs1,
                      ushort_t* __restrict__ h1b) {
    int idx = blockIdx.x * 256 + threadIdx.x;
    if (idx >= T_EX * 512) return;
    int c = idx & 511, t = idx >> 9;
    float s = 0.f;
    for (int m = 0; m < MM; ++m) s += Y1[(size_t)(m * T_EX + t) * 512 + c];
    float base = s + bs1[c];
    if (t == 0) {
        for (int m = 0; m < MM; ++m) {
            float val = base - Y1[(size_t)(m * T_EX) * 512 + c];
            h1b[(size_t)(m * T_EX) * 512 + c] = f2bf(lrelu(val));
        }
    } else {
        ushort_t v = f2bf(lrelu(base));
        for (int m = 0; m < MM; ++m)
            h1b[(size_t)(m * T_EX + t) * 512 + c] = v;
    }
}

// ---------- fused s2+h2 ----------
__global__ void sh2_k(const float* __restrict__ Y2, const float* __restrict__ bs2,
                      float* __restrict__ h2) {
    int idx = blockIdx.x * 256 + threadIdx.x;
    if (idx >= T_EX * 256) return;
    int c = idx & 255, t = idx >> 8;
    float s = 0.f;
    for (int m = 0; m < MM; ++m) s += Y2[(size_t)(m * T_EX + t) * 256 + c];
    float base = s + bs2[c];
    if (t == 0) {
        for (int m = 0; m < MM; ++m)
            h2[(size_t)(m * T_EX) * 256 + c] = lrelu(base - Y2[(size_t)(m * T_EX) * 256 + c]);
    } else {
        float v = lrelu(base);
        for (int m = 0; m < MM; ++m) h2[(size_t)(m * T_EX + t) * 256 + c] = v;
    }
}

__global__ void v1vx_k(const float* __restrict__ h2, const float* __restrict__ xhat,
                       float* __restrict__ V1, float* __restrict__ Vx) {
    int idx = blockIdx.x * 256 + threadIdx.x;
    if (idx >= DD * MM) return;
    int m = idx % MM, d = idx / MM;
    float mx = -INFINITY;
    for (int t = 0; t < T_EX; ++t) mx = fmaxf(mx, h2[(m * T_EX + t) * 256 + d]);
    V1[idx] = mx;
    Vx[idx] = mx + xhat[idx];
}

__global__ void lin88_k(const float* __restrict__ Wg, const float* __restrict__ bg,
                        const float* __restrict__ Wh, const float* __restrict__ bh,
                        const float* __restrict__ Vin, float* __restrict__ Gout,
                        float* __restrict__ Hout) {
    int idx = blockIdx.x * 256 + threadIdx.x;
    if (idx >= DD * MM) return;
    const float* W = blockIdx.y ? Wh : Wg;
    const float* bias = blockIdx.y ? bh : bg;
    float* out = blockIdx.y ? Hout : Gout;
    int m = idx % MM, o = idx / MM;
    const float* wr = W + o * 256;
    float acc = bias[o];
    for (int i = 0; i < 256; ++i) acc = fmaf(wr[i], Vin[i * MM + m], acc);
    out[idx] = acc;
}

// ---------- fused Smat row + softmax ----------
__global__ void smsm_k(const float* __restrict__ Hh, const float* __restrict__ G,
                       float* __restrict__ A2) {
    int j = blockIdx.x;
    int tid = threadIdx.x;   // 128
    __shared__ float row[96];
    __shared__ float red[128];
    for (int i = tid; i < MM; i += 128) {
        float acc = 0.f;
        for (int c = 0; c < 256; ++c) acc = fmaf(Hh[c * MM + j], G[c * MM + i], acc);
        row[i] = acc;
    }
    __syncthreads();
    float val = (tid < MM) ? row[tid] : -INFINITY;
    red[tid] = val; __syncthreads();
    for (int s = 64; s > 0; s >>= 1) {
        if (tid < s) red[tid] = fmaxf(red[tid], red[tid + s]);
        __syncthreads();
    }
    float mx = red[0]; __syncthreads();
    float e = (tid < MM) ? expf(val - mx) : 0.f;
    red[tid] = e; __syncthreads();
    for (int s = 64; s > 0; s >>= 1) {
        if (tid < s) red[tid] += red[tid + s];
        __syncthreads();
    }
    float inv = 1.f / red[0];
    if (tid < MM) A2[j * MM + tid] = e * inv;
}

__global__ void t1_k(const float* __restrict__ V1, const float* __restrict__ wc1,
                     float* __restrict__ t1) {
    int idx = blockIdx.x * 256 + threadIdx.x;
    if (idx >= MM * 384) return;
    int c = idx % 384, m = idx / 384;
    float acc = 0.f;
    for (int d = 0; d < 256; ++d) acc = fmaf(V1[d * MM + m], wc1[d * 384 + c], acc);
    t1[idx] = acc;
}

__global__ void c1_k(const float* __restrict__ A2, const float* __restrict__ t1,
                     const float* __restrict__ bc1, float* __restrict__ c1) {
    int idx = blockIdx.x * 256 + threadIdx.x;
    if (idx >= MM * 384) return;
    int c = idx % 384, j = idx / 384;
    float acc = bc1[c];
    for (int i = 0; i < MM; ++i) acc = fmaf(A2[j * MM + i], t1[i * 384 + c], acc);
    c1[idx] = lrelu(acc);
}

__global__ void t2_k(const float* __restrict__ c1, const float* __restrict__ wc2,
                     float* __restrict__ t2) {
    int idx = blockIdx.x * 256 + threadIdx.x;
    if (idx >= MM * 256) return;
    int c = idx % 256, m = idx / 256;
    const float* cr = c1 + m * 384;
    float acc = 0.f;
    for (int d = 0; d < 384; ++d) acc = fmaf(cr[d], wc2[d * 256 + c], acc);
    t2[idx] = acc;
}

__global__ void v2_k(const float* __restrict__ A2, const float* __restrict__ t2,
                     const float* __restrict__ bc2, float* __restrict__ V2m) {
    int idx = blockIdx.x * 256 + threadIdx.x;
    if (idx >= MM * 256) return;
    int c = idx % 256, j = idx / 256;
    float acc = bc2[c];
    for (int i = 0; i < MM; ++i) acc = fmaf(A2[j * MM + i], t2[i * 256 + c], acc);
    V2m[idx] = lrelu(acc);
}

__global__ void final_k(const float* __restrict__ Xf2, const float* __restrict__ V2m,
                        float* __restrict__ out) {
    __shared__ float red[256];
    float acc = 0.f;
    for (int idx = threadIdx.x; idx < DD * MM; idx += 256)
        acc = fmaf(Xf2[idx], V2m[idx], acc);
    red[threadIdx.x] = acc; __syncthreads();
    for (int s = 128; s > 0; s >>= 1) {
        if (threadIdx.x < s) red[threadIdx.x] += red[threadIdx.x + s];
        __syncthreads();
    }
    if (threadIdx.x == 0) out[0] = red[0];
}

extern "C" void kernel_launch(void* const* d_in, const int* in_sizes, int n_in,
                              void* d_out, int out_size, void* d_ws, size_t ws_size,
                              hipStream_t stream) {
    const float* search = (const float*)d_in[0];
    const float* exemp  = (const float*)d_in[1];
    const float* aw1 = (const float*)d_in[2];  const float* ab1 = (const float*)d_in[3];
    const float* aw2 = (const float*)d_in[4];  const float* ab2 = (const float*)d_in[5];
    const float* aw3 = (const float*)d_in[6];  const float* ab3 = (const float*)d_in[7];
    const float* aw4 = (const float*)d_in[8];  const float* ab4 = (const float*)d_in[9];
    const float* aw5 = (const float*)d_in[10]; const float* ab5 = (const float*)d_in[11];
    const float* wcd = (const float*)d_in[12]; const float* bcd = (const float*)d_in[13];
    const float* wt  = (const float*)d_in[14]; const float* bt  = (const float*)d_in[15];
    const float* ws1 = (const float*)d_in[16]; const float* bs1 = (const float*)d_in[17];
    const float* ws2 = (const float*)d_in[18]; const float* bs2 = (const float*)d_in[19];
    const float* wg  = (const float*)d_in[20]; const float* bg  = (const float*)d_in[21];
    const float* wh  = (const float*)d_in[22]; const float* bh  = (const float*)d_in[23];
    const float* wc1 = (const float*)d_in[24]; const float* bc1 = (const float*)d_in[25];
    const float* wc2 = (const float*)d_in[26]; const float* bc2 = (const float*)d_in[27];

    float* ws = (float*)d_ws;
    float* R1 = ws;
    float* R2 = ws + 3870720;
    float* R3 = ws + 7544832;
    float* Wg = ws + 8628864;

    ushort_t* in1p  = (ushort_t*)R1;
    ushort_t* c1out = (ushort_t*)R2;
    ushort_t* p1out = (ushort_t*)R3;
    ushort_t* c2out = (ushort_t*)R1;
    ushort_t* p2out = (ushort_t*)R2;
    ushort_t* c3out = (ushort_t*)(R2 + 775200);
    ushort_t* c4out = (ushort_t*)R1;
    ushort_t* c5out = (ushort_t*)R3;
    ushort_t* WT    = (ushort_t*)Wg;

    // ---- conv stack: 1-wave blocks, coalesced px-major staging ----
    zfill_k<<<(965500 + 255) / 256, 256, 0, stream>>>((float4*)R1, 965500);
    prep1_k<<<(BATCH * H0 * W0 + 255) / 256, 256, 0, stream>>>(search, exemp, in1p);
    wprep_k<<<(4608 + 255) / 256, 256, 0, stream>>>(aw1, WT, 11, 12, 11, 4, 3, 18, 4608, 64);
    conv_mfma12<64, false, 4><<<dim3(1792, 1), 64, 0, stream>>>(
        in1p, WT, ab1, c1out, HP1, WP1, 4, W1, H1 * W1, BATCH * H1 * W1, 9, 12, H1, W1, 0, 64);
    zfill_k<<<(270504 + 255) / 256, 256, 0, stream>>>((float4*)R3, 270504);
    pool_nhwc<<<(BATCH * 64 * H1P * W1P + 255) / 256, 256, 0, stream>>>(
        c1out, p1out, 64, H1, W1, H1P, W1P, 51, 39, 2);
    wprep_k<<<(38400 + 255) / 256, 256, 0, stream>>>(aw2, WT, 5, 5, 5, 64, 64, 50, 38400, 192);
    conv_mfma12<64, true, 1><<<dim3(437, 3), 64, 0, stream>>>(
        p1out, WT, ab2, c2out, 51, 39, 64, W1P, H1P * W1P, BATCH * H1P * W1P, 25, 5, H1P, W1P, 0, 192);
    zfill_k<<<(581400 + 255) / 256, 256, 0, stream>>>((float4*)R2, 581400);
    pool_nhwc<<<(BATCH * 192 * H2P * W2P + 255) / 256, 256, 0, stream>>>(
        c2out, p2out, 192, H1P, W1P, H2P, W2P, 25, 19, 1);
    wprep_k<<<(82944 + 255) / 256, 256, 0, stream>>>(aw3, WT, 3, 3, 3, 192, 192, 54, 82944, 384);
    conv_mfma12<64, true, 1><<<dim3(104, 6), 64, 0, stream>>>(
        p2out, WT, ab3, c3out, 25, 19, 192, W2P, H2P * W2P, BATCH * H2P * W2P, 27, 3, 25, 19, 1, 384);
    zfill_k<<<(258400 + 255) / 256, 256, 0, stream>>>((float4*)R1, 258400);
    wprep_k<<<(110592 + 255) / 256, 256, 0, stream>>>(aw4, WT, 3, 3, 3, 384, 384, 108, 110592, 256);
    conv_mfma12<32, true, 1><<<dim3(104, 8), 64, 0, stream>>>(
        c3out, WT, ab4, c4out, 25, 19, 384, W2P, H2P * W2P, BATCH * H2P * W2P, 54, 3, 25, 19, 1, 256);
    wprep_k<<<(73728 + 255) / 256, 256, 0, stream>>>(aw5, WT, 3, 3, 3, 256, 256, 72, 73728, 256);
    conv_mfma12<32, true, 1><<<dim3(104, 8), 64, 0, stream>>>(
        c4out, WT, ab5, c5out, 25, 19, 256, W2P, H2P * W2P, BATCH * H2P * W2P, 36, 3, H2P, W2P, 0, 256);

    // ---- tail region layout in R1 ----
    float*    P      = R1 + 2417664;
    ushort_t* PB     = (ushort_t*)(R1 + 2800640);
    ushort_t* XfPad  = (ushort_t*)(R1 + 2992128);   // rows 0 & 89 zeroed by first R1 zfill
    float*    xc     = R1 + 3003648;

    ushort_t* WS1T = (ushort_t*)Wg;
    ushort_t* WS2T = (ushort_t*)(Wg + 65536);
    ushort_t* WCDT = (ushort_t*)(Wg + 131072);
    wprep_gemm_k<<<(57344 + 255) / 256, 256, 0, stream>>>(ws1, ws2, wcd, WS1T, WS2T, WCDT);

    pool5_k<<<(BATCH * 256 * MM + 255) / 256, 256, 0, stream>>>(c5out, P, PB, XfPad);
    float* Xf2 = P;

    float* xhat = R1 + 1024;
    float* Y1   = R1 + 23552;
    ushort_t* h1b = (ushort_t*)(R1 + 752640);
    float* Y2   = R1 + 1473536;
    float* h2   = R1 + 1838080;
    float* V1   = R1 + 2198528;
    float* Vx   = R1 + 2221056;
    float* G    = R1 + 2243584;
    float* Hh   = R1 + 2266112;
    float* A2   = R1 + 2296832;
    float* t1   = R1 + 2305024;
    float* c1   = R1 + 2338816;
    float* t2   = R1 + 2372608;
    float* V2m  = R1 + 2395136;

    gemm_mfma3<0, true, false><<<dim3(2, 4), 256, 0, stream>>>(
        XfPad, WCDT, bcd, xc, 256, MM, 24, 1, MM);
    xhat2_k<<<(DD * MM + 255) / 256, 256, 0, stream>>>(xc, wt, bt, xhat);

    gemm_mfma3<1, false, true><<<dim3(22, 8), 256, 0, stream>>>(
        PB, WS1T, nullptr, Y1, 256, TM, 8, 512, 1);
    sh1_k<<<(T_EX * 512 + 255) / 256, 256, 0, stream>>>(Y1, bs1, h1b);
    gemm_mfma3<0, false, true><<<dim3(22, 4), 256, 0, stream>>>(
        h1b, WS2T, nullptr, Y2, 512, TM, 16, 256, 1);
    sh2_k<<<(T_EX * 256 + 255) / 256, 256, 0, stream>>>(Y2, bs2, h2);
    v1vx_k<<<(DD * MM + 255) / 256, 256, 0, stream>>>(h2, xhat, V1, Vx);

    lin88_k<<<dim3((DD * MM + 255) / 256, 2), 256, 0, stream>>>(wg, bg, wh, bh, Vx, G, Hh);
    smsm_k<<<MM, 128, 0, stream>>>(Hh, G, A2);

    t1_k<<<(MM * 384 + 255) / 256, 256, 0, stream>>>(V1, wc1, t1);
    c1_k<<<(MM * 384 + 255) / 256, 256, 0, stream>>>(A2, t1, bc1, c1);
    t2_k<<<(MM * 256 + 255) / 256, 256, 0, stream>>>(c1, wc2, t2);
    v2_k<<<(MM * 256 + 255) / 256, 256, 0, stream>>>(A2, t2, bc2, V2m);

    final_k<<<1, 256, 0, stream>>>(Xf2, V2m, (float*)d_out);
}

// Round 7
// 548.191 us; speedup vs baseline: 1.1063x; 1.1063x over previous
//
#include <hip/hip_runtime.h>
#include <hip/hip_bf16.h>
#include <math.h>

// ---------- dims ----------
#define BATCH 17
#define T_EX 16
#define H0 383
#define W0 287
#define C1 64
#define H1 95
#define W1 71
#define H1P 47
#define W1P 35
#define C2 192
#define H2P 23
#define W2P 17
#define C3 384
#define C45 256
#define H5P 11
#define W5P 8
#define DD 256
#define MM 88
#define TM 1408

#define HP1 389
#define WP1 292

typedef unsigned short ushort_t;
typedef __attribute__((ext_vector_type(8))) short short8;
typedef __attribute__((ext_vector_type(4))) float f32x4;

__device__ __forceinline__ float lrelu(float v) { return v > 0.f ? v : 0.01f * v; }

__device__ __forceinline__ ushort_t f2bf(float f) {
    unsigned int u = __float_as_uint(f);
    unsigned int r = (u + 0x7fffu + ((u >> 16) & 1u)) >> 16;
    return (ushort_t)r;
}
__device__ __forceinline__ float b2f(ushort_t b) {
    return __uint_as_float(((unsigned int)b) << 16);
}
__device__ __forceinline__ short8 ld16(const ushort_t* p) { return *(const short8*)p; }
__device__ __forceinline__ short8 ld2x8(const ushort_t* p) {
    union { uint2 u[2]; short8 s; } uu;
    uu.u[0] = *(const uint2*)p;
    uu.u[1] = *(const uint2*)(p + 4);
    return uu.s;
}
// async global -> LDS, 16B per lane; LDS dest = wave-uniform base + lane*16
__device__ __forceinline__ void async_cp16(ushort_t* l, const ushort_t* g) {
    __builtin_amdgcn_global_load_lds(
        (const __attribute__((address_space(1))) void*)g,
        (__attribute__((address_space(3))) void*)l, 16, 0, 0);
}

// ---------- zero fill ----------
__global__ void zfill_k(float4* __restrict__ p, int n4) {
    int idx = blockIdx.x * 256 + threadIdx.x;
    if (idx < n4) p[idx] = (float4){0.f, 0.f, 0.f, 0.f};
}

// ---------- conv1 input prep: fp32 NCHW -> bf16 NHWC padded (C=4, pad 2) ----------
__global__ void prep1_k(const float* __restrict__ search, const float* __restrict__ exemp,
                        ushort_t* __restrict__ out) {
    int idx = blockIdx.x * 256 + threadIdx.x;
    if (idx >= BATCH * H0 * W0) return;
    int ix = idx % W0; int t = idx / W0;
    int iy = t % H0; int b = t / H0;
    const float* src = (b == 0) ? search : exemp + (size_t)(b - 1) * 3 * H0 * W0;
    const int hw = H0 * W0;
    float v0 = src[iy * W0 + ix];
    float v1 = src[hw + iy * W0 + ix];
    float v2 = src[2 * hw + iy * W0 + ix];
    ushort4 o;
    o.x = f2bf(v0); o.y = f2bf(v1); o.z = f2bf(v2); o.w = 0;
    *(ushort4*)&out[(((size_t)b * HP1 + iy + 2) * WP1 + ix + 2) * 4] = o;
}

// ---------- conv weight prep: OIHW fp32 -> bf16 MFMA tiles, K-order (ky,kx,ic) ----------
__global__ void wprep_k(const float* __restrict__ w, ushort_t* __restrict__ out,
                        int KH, int KWl, int KWr, int CINl, int CINr,
                        int NKS, int nch, int OCr) {
    int idx = blockIdx.x * 256 + threadIdx.x;
    if (idx >= nch) return;
    int c = idx & 255;
    int rest = idx >> 8;
    int ks = rest % NKS;
    int ocb = rest / NKS;
    int k8 = c >> 6, m = c & 63;
    int oc = ocb * 64 + m;
    int KWC = KWl * CINl;
    ushort_t* o = out + (size_t)idx * 8;
#pragma unroll
    for (int j = 0; j < 8; ++j) {
        int kg = ks * 32 + k8 * 8 + j;
        int ky = kg / KWC; int rem = kg - ky * KWC;
        int kx = rem / CINl; int ic = rem - kx * CINl;
        float v = 0.f;
        if (oc < OCr && ky < KH && kx < KWr && ic < CINr)
            v = w[(((size_t)oc * CINr + ic) * KH + ky) * KWr + kx];
        o[j] = f2bf(v);
    }
}

// ---------- fused gemm weight prep (ws1 | ws2 | wcd), tiled layout ----------
__global__ void wprep_gemm_k(const float* __restrict__ ws1, const float* __restrict__ ws2,
                             const float* __restrict__ wcd, ushort_t* __restrict__ WS1T,
                             ushort_t* __restrict__ WS2T, ushort_t* __restrict__ WCDT) {
    int idx = blockIdx.x * 256 + threadIdx.x;
    const float* src; ushort_t* dst; int NKS, mode = 0, sa = 1, sk = 0, base;
    if (idx < 16384)       { src = ws1; dst = WS1T; NKS = 8;  sk = 512; base = idx; }
    else if (idx < 32768)  { src = ws2; dst = WS2T; NKS = 16; sk = 256; base = idx - 16384; }
    else if (idx < 57344)  { src = wcd; dst = WCDT; NKS = 24; mode = 1; base = idx - 32768; }
    else return;
    int c = base & 255;
    int rest = base >> 8;
    int ks = rest % NKS;
    int ocb = rest / NKS;
    int k8 = c >> 6, m = c & 63;
    int oc = ocb * 64 + m;
    ushort_t* o = dst + (size_t)base * 8;
#pragma unroll
    for (int j = 0; j < 8; ++j) {
        int kg = ks * 32 + k8 * 8 + j;
        float v;
        if (mode == 0) v = src[(size_t)oc * sa + (size_t)kg * sk];
        else           v = src[(size_t)oc * 768 + (kg & 255) * 3 + (kg >> 8)];
        o[j] = f2bf(v);
    }
}

// ====================================================================
// bf16 MFMA implicit-GEMM conv, v13 = EXACT v5 (547us-verified) scaffold
// with ONE surgical change in the A16 path: B staging is coalesced
// px-major with a conflict-free XOR swizzle.
//  - v12's counters isolated the failure: px-major write at
//    g8*1024+po*16 bytes = 8-way bank conflict (2.0e7 conflicts).
//  - Fix (rule #21, both-sides-same-involution): store (kg,px) at
//    shorts kg*512 + (px^kg)*8; read with the same XOR.
//    writes: per 16-lane gang each 16B slot-class hit exactly 2x ->
//    2/bank = free (m136). reads: permutation of v5's contiguous
//    256B read -> identical (zero-conflict) bank profile.
//  - Global side: K-step 64 divides C for conv2-5 -> offs[ks*8+g8]
//    = base+g8*8 -> each 8-lane po-group reads contiguous 128B
//    (16 lines/inst vs 64 before).
//  - A-tile DMA, barriers, grids, conv1 path, epilogue: v5 verbatim.
//  - Same K-order/accumulation order -> bitwise-identical output.
// ====================================================================
template <int STRIDE, bool A16>
__global__ __launch_bounds__(256) void conv_mfma13(
    const ushort_t* __restrict__ inp, const ushort_t* __restrict__ wt,
    const float* __restrict__ bias, ushort_t* __restrict__ out,
    int Hp, int Wp, int C, int Wout, int HW, int NKS2, int KWl,
    int OHp, int OWp, int OPAD, int COUT) {
    const int tid = threadIdx.x;
    const int wv = tid >> 6, lane = tid & 63;
    const int quad = lane >> 4, l16 = lane & 15;
    const int n_blk = blockIdx.x * 64;
    const int ocb = blockIdx.y;
    const int b = blockIdx.z;

    __shared__ ushort_t As[2][4096];   // [buf][2 tiles x 2048 bf16] = 8 KB/buf
    __shared__ ushort_t Bs[2][4096];
    __shared__ int offs[432];

    const int KWC = KWl * C;
    for (int g = tid; g < NKS2 * 8; g += 256) {
        int kg = g * 8;
        int ky = kg / KWC; int rem = kg - ky * KWC;
        int kx = rem / C; int c8 = rem - kx * C;
        offs[g] = (ky * Wp + kx) * C + c8;
    }

    const ushort_t* inb = inp + (size_t)b * Hp * Wp * C;

    // ---- A16 staging roles: px-major coalesced ----
    const int g8 = lane & 7, po = lane >> 3;
    int np0 = n_blk + wv * 16 + po;      if (np0 >= HW) np0 = HW - 1;
    int np1 = n_blk + wv * 16 + 8 + po;  if (np1 >= HW) np1 = HW - 1;
    const ushort_t* bsrc0;
    const ushort_t* bsrc1;
    {
        int oy0 = np0 / Wout, ox0 = np0 - oy0 * Wout;
        int oy1 = np1 / Wout, ox1 = np1 - oy1 * Wout;
        bsrc0 = inb + (size_t)(oy0 * STRIDE * Wp + ox0 * STRIDE) * C;
        bsrc1 = inb + (size_t)(oy1 * STRIDE * Wp + ox1 * STRIDE) * C;
    }
    // swizzled LDS dest slots (shorts): kg*512 + (px^kg)*8
    const int ws0 = g8 * 512 + (((wv * 16 + po) ^ g8) * 8);
    const int ws1 = g8 * 512 + (((wv * 16 + 8 + po) ^ g8) * 8);

    // ---- !A16 staging role (v5 conv1 path): per-lane pixel ----
    int n_g = n_blk + lane;
    int n_gc = n_g < HW ? n_g : HW - 1;
    int oyl = n_gc / Wout, oxl = n_gc - oyl * Wout;
    const int base0 = (oyl * STRIDE * Wp + oxl * STRIDE) * C;

    f32x4 acc[4];
#pragma unroll
    for (int cn = 0; cn < 4; ++cn) acc[cn] = (f32x4){0.f, 0.f, 0.f, 0.f};

    const ushort_t* wblk = wt + (size_t)ocb * (size_t)NKS2 * 4096;

    __syncthreads();   // offs ready

    // ---- prologue: stage step 0 into buf 0 ----
    {
        const ushort_t* aS = wblk + tid * 8;
        async_cp16(&As[0][tid * 8], aS);
        async_cp16(&As[0][2048 + tid * 8], aS + 2048);
        if constexpr (A16) {
            short8 r0v = ld16(bsrc0 + offs[g8]);
            short8 r1v = ld16(bsrc1 + offs[g8]);
            *(short8*)&Bs[0][ws0] = r0v;
            *(short8*)&Bs[0][ws1] = r1v;
        } else {
            const int o0 = offs[wv], o1 = offs[4 + wv];
            *(short8*)&Bs[0][tid * 8] = ld2x8(inb + base0 + o0);
            *(short8*)&Bs[0][2048 + tid * 8] = ld2x8(inb + base0 + o1);
        }
    }
    __syncthreads();

    for (int ks2 = 0; ks2 < NKS2; ++ks2) {
        const int cur = ks2 & 1, nxt = cur ^ 1;
        const bool more = (ks2 + 1 < NKS2);
        short8 rb0, rb1;
        // stage next step (A via DMA as in v5; B loads issued early, T14)
        if (more) {
            const ushort_t* aS = wblk + (size_t)(ks2 + 1) * 4096 + tid * 8;
            async_cp16(&As[nxt][tid * 8], aS);
            async_cp16(&As[nxt][2048 + tid * 8], aS + 2048);
            if constexpr (A16) {
                rb0 = ld16(bsrc0 + offs[(ks2 + 1) * 8 + g8]);
                rb1 = ld16(bsrc1 + offs[(ks2 + 1) * 8 + g8]);
            } else {
                const int o0 = offs[(ks2 + 1) * 8 + wv], o1 = offs[(ks2 + 1) * 8 + 4 + wv];
                *(short8*)&Bs[nxt][tid * 8] = ld2x8(inb + base0 + o0);
                *(short8*)&Bs[nxt][2048 + tid * 8] = ld2x8(inb + base0 + o1);
            }
        }
        // compute: 2 half-tiles x 4 col-tiles = 32 MFMAs / block
#pragma unroll
        for (int h = 0; h < 2; ++h) {
            const short8 af = *(const short8*)&As[cur][h * 2048 + (quad * 64 + wv * 16 + l16) * 8];
#pragma unroll
            for (int cn = 0; cn < 4; ++cn) {
                int bidx;
                if constexpr (A16)
                    bidx = h * 2048 + quad * 512 + (((cn * 16 + l16) ^ (h * 4 + quad)) * 8);
                else
                    bidx = h * 2048 + (quad * 64 + cn * 16 + l16) * 8;
                const short8 bfr = *(const short8*)&Bs[cur][bidx];
                acc[cn] = __builtin_amdgcn_mfma_f32_16x16x32_bf16(af, bfr, acc[cn], 0, 0, 0);
            }
        }
        // B writes land after compute (buf nxt free since barrier of step ks2-1)
        if constexpr (A16) {
            if (more) {
                *(short8*)&Bs[nxt][ws0] = rb0;
                *(short8*)&Bs[nxt][ws1] = rb1;
            }
        }
        __syncthreads();
    }

    const int oc0 = ocb * 64 + wv * 16 + quad * 4;
    const float bi0 = bias[oc0], bi1 = bias[oc0 + 1], bi2 = bias[oc0 + 2], bi3 = bias[oc0 + 3];
#pragma unroll
    for (int cn = 0; cn < 4; ++cn) {
        int n = n_blk + cn * 16 + l16;
        if (n < HW) {
            int y = n / Wout, x = n - y * Wout;
            size_t base = (((size_t)b * OHp + y + OPAD) * OWp + x + OPAD) * COUT + oc0;
            ushort4 o;
            o.x = f2bf(fmaxf(acc[cn][0] + bi0, 0.f));
            o.y = f2bf(fmaxf(acc[cn][1] + bi1, 0.f));
            o.z = f2bf(fmaxf(acc[cn][2] + bi2, 0.f));
            o.w = f2bf(fmaxf(acc[cn][3] + bi3, 0.f));
            *(ushort4*)&out[base] = o;
        }
    }
}

// ====================================================================
// Generic bf16 MFMA GEMM: A direct from global (tiled), B LDS dbuf.
// ====================================================================
template <int MODE, bool HASBIAS, bool SC1>
__global__ __launch_bounds__(256) void gemm_mfma3(
    const ushort_t* __restrict__ Bsrc, const ushort_t* __restrict__ wt,
    const float* __restrict__ bias, float* __restrict__ out,
    int RS, int N, int NKS, int sn, int sc) {
    const int tid = threadIdx.x;
    const int wv = tid >> 6, lane = tid & 63;
    const int quad = lane >> 4, l16 = lane & 15;
    const int n_blk = blockIdx.x * 64;
    const int ocb = blockIdx.y;

    __shared__ ushort_t Bs[2][2048];

    int n_g = n_blk + lane;
    int n_gc = n_g < N ? n_g : N - 1;
    int row = (MODE == 1) ? (1 + (n_gc & 15)) * MM + (n_gc >> 4) : n_gc;
    const size_t base0 = (size_t)row * RS;

    f32x4 acc[4];
#pragma unroll
    for (int cn = 0; cn < 4; ++cn) acc[cn] = (f32x4){0.f, 0.f, 0.f, 0.f};

    const ushort_t* wblk = wt + (size_t)ocb * NKS * 2048;
    const int afrag = (quad * 64 + wv * 16 + l16) * 8;

    short8 a0 = ld16(wblk + afrag);
    *(short8*)&Bs[0][tid * 8] = ld16(Bsrc + base0 + wv * 8);
    __syncthreads();

    for (int ks = 0; ks < NKS; ++ks) {
        const int cur = ks & 1, nxt = cur ^ 1;
        short8 a1, bn;
        const bool more = (ks + 1 < NKS);
        if (more) {
            a1 = ld16(wblk + (ks + 1) * 2048 + afrag);
            bn = ld16(Bsrc + base0 + (ks + 1) * 32 + wv * 8);
        }
#pragma unroll
        for (int cn = 0; cn < 4; ++cn) {
            const short8 bfr = *(const short8*)&Bs[cur][(quad * 64 + cn * 16 + l16) * 8];
            acc[cn] = __builtin_amdgcn_mfma_f32_16x16x32_bf16(a0, bfr, acc[cn], 0, 0, 0);
        }
        if (more) *(short8*)&Bs[nxt][tid * 8] = bn;
        a0 = a1;
        __syncthreads();
    }

    const int oc0 = ocb * 64 + wv * 16 + quad * 4;
    float bb[4] = {0.f, 0.f, 0.f, 0.f};
    if (HASBIAS) { bb[0] = bias[oc0]; bb[1] = bias[oc0+1]; bb[2] = bias[oc0+2]; bb[3] = bias[oc0+3]; }
#pragma unroll
    for (int cn = 0; cn < 4; ++cn) {
        int n = n_blk + cn * 16 + l16;
        if (n < N) {
            if (SC1) {
                float4 o;
                o.x = acc[cn][0] + bb[0]; o.y = acc[cn][1] + bb[1];
                o.z = acc[cn][2] + bb[2]; o.w = acc[cn][3] + bb[3];
                *(float4*)&out[(size_t)n * sn + oc0] = o;
            } else {
#pragma unroll
                for (int reg = 0; reg < 4; ++reg)
                    out[(size_t)n * sn + (size_t)(oc0 + reg) * sc] = acc[cn][reg] + bb[reg];
            }
        }
    }
}

// ---------- maxpool k3 s2 VALID, NHWC bf16 ----------
__global__ void pool_nhwc(const ushort_t* __restrict__ in, ushort_t* __restrict__ out,
                          int C, int Hin, int Win, int Hout, int Wout,
                          int OHp, int OWp, int OPAD) {
    int total = BATCH * C * Hout * Wout;
    int idx = blockIdx.x * 256 + threadIdx.x;
    if (idx >= total) return;
    int c = idx % C; int r = idx / C;
    int x = r % Wout; r /= Wout;
    int y = r % Hout; int b = r / Hout;
    const int rs = Win * C;
    const ushort_t* p = in + (((size_t)b * Hin + 2 * y) * Win + 2 * x) * C + c;
    float m = b2f(p[0]);
    m = fmaxf(m, b2f(p[C])); m = fmaxf(m, b2f(p[2 * C]));
    m = fmaxf(m, b2f(p[rs])); m = fmaxf(m, b2f(p[rs + C])); m = fmaxf(m, b2f(p[rs + 2 * C]));
    m = fmaxf(m, b2f(p[2 * rs])); m = fmaxf(m, b2f(p[2 * rs + C])); m = fmaxf(m, b2f(p[2 * rs + 2 * C]));
    out[(((size_t)b * OHp + y + OPAD) * OWp + x + OPAD) * C + c] = f2bf(m);
}

// ---------- pool5: NHWC bf16 -> P fp32 [b][m][d] + PB bf16 + XfPad ----------
__global__ void pool5_k(const ushort_t* __restrict__ in, float* __restrict__ P,
                        ushort_t* __restrict__ PB, ushort_t* __restrict__ XfPad) {
    int total = BATCH * 256 * MM;
    int idx = blockIdx.x * 256 + threadIdx.x;
    if (idx >= total) return;
    int c = idx % 256; int r = idx / 256;
    int x = r % W5P; r /= W5P;
    int y = r % H5P; int b = r / H5P;
    const int rs = W2P * 256;
    const ushort_t* p = in + (((size_t)b * H2P + 2 * y) * W2P + 2 * x) * 256 + c;
    float m = b2f(p[0]);
    m = fmaxf(m, b2f(p[256])); m = fmaxf(m, b2f(p[512]));
    m = fmaxf(m, b2f(p[rs])); m = fmaxf(m, b2f(p[rs + 256])); m = fmaxf(m, b2f(p[rs + 512]));
    m = fmaxf(m, b2f(p[2 * rs])); m = fmaxf(m, b2f(p[2 * rs + 256])); m = fmaxf(m, b2f(p[2 * rs + 512]));
    int mm = y * W5P + x;
    size_t o = ((size_t)b * MM + mm) * 256 + c;
    P[o] = m;
    ushort_t mb = f2bf(m);
    PB[o] = mb;
    if (b == 0) XfPad[(size_t)(mm + 1) * 256 + c] = mb;
}

// ---------- xhat with in-block vmax (fused) ----------
__global__ void xhat2_k(const float* __restrict__ xc, const float* __restrict__ wt,
                        const float* __restrict__ bt, float* __restrict__ xhat) {
    __shared__ float lv[256];
    {
        int j = threadIdx.x;
        const float* xr = xc + (size_t)j * MM;
        float mx = xr[0];
        for (int k = 1; k < MM; ++k) mx = fmaxf(mx, xr[k]);
        lv[j] = mx;
    }
    __syncthreads();
    int idx = blockIdx.x * 256 + threadIdx.x;
    if (idx >= DD * MM) return;
    int k = idx % MM, o = idx / MM;
    float acc = bt[o];
    for (int i = 0; i < 256; ++i) acc = fmaf(lv[i], wt[(i * 256 + o) * MM + k], acc);
    xhat[idx] = acc;
}

// ---------- fused s1+h1 ----------
__global__ void sh1_k(const float* __restrict__ Y1, const float* __restrict__ bs1,
                      ushort_t* __restrict__ h1b) {
    int idx = blockIdx.x * 256 + threadIdx.x;
    if (idx >= T_EX * 512) return;
    int c = idx & 511, t = idx >> 9;
    float s = 0.f;
    for (int m = 0; m < MM; ++m) s += Y1[(size_t)(m * T_EX + t) * 512 + c];
    float base = s + bs1[c];
    if (t == 0) {
        for (int m = 0; m < MM; ++m) {
            float val = base - Y1[(size_t)(m * T_EX) * 512 + c];
            h1b[(size_t)(m * T_EX) * 512 + c] = f2bf(lrelu(val));
        }
    } else {
        ushort_t v = f2bf(lrelu(base));
        for (int m = 0; m < MM; ++m)
            h1b[(size_t)(m * T_EX + t) * 512 + c] = v;
    }
}

// ---------- fused s2+h2 ----------
__global__ void sh2_k(const float* __restrict__ Y2, const float* __restrict__ bs2,
                      float* __restrict__ h2) {
    int idx = blockIdx.x * 256 + threadIdx.x;
    if (idx >= T_EX * 256) return;
    int c = idx & 255, t = idx >> 8;
    float s = 0.f;
    for (int m = 0; m < MM; ++m) s += Y2[(size_t)(m * T_EX + t) * 256 + c];
    float base = s + bs2[c];
    if (t == 0) {
        for (int m = 0; m < MM; ++m)
            h2[(size_t)(m * T_EX) * 256 + c] = lrelu(base - Y2[(size_t)(m * T_EX) * 256 + c]);
    } else {
        float v = lrelu(base);
        for (int m = 0; m < MM; ++m) h2[(size_t)(m * T_EX + t) * 256 + c] = v;
    }
}

__global__ void v1vx_k(const float* __restrict__ h2, const float* __restrict__ xhat,
                       float* __restrict__ V1, float* __restrict__ Vx) {
    int idx = blockIdx.x * 256 + threadIdx.x;
    if (idx >= DD * MM) return;
    int m = idx % MM, d = idx / MM;
    float mx = -INFINITY;
    for (int t = 0; t < T_EX; ++t) mx = fmaxf(mx, h2[(m * T_EX + t) * 256 + d]);
    V1[idx] = mx;
    Vx[idx] = mx + xhat[idx];
}

__global__ void lin88_k(const float* __restrict__ Wg, const float* __restrict__ bg,
                        const float* __restrict__ Wh, const float* __restrict__ bh,
                        const float* __restrict__ Vin, float* __restrict__ Gout,
                        float* __restrict__ Hout) {
    int idx = blockIdx.x * 256 + threadIdx.x;
    if (idx >= DD * MM) return;
    const float* W = blockIdx.y ? Wh : Wg;
    const float* bias = blockIdx.y ? bh : bg;
    float* out = blockIdx.y ? Hout : Gout;
    int m = idx % MM, o = idx / MM;
    const float* wr = W + o * 256;
    float acc = bias[o];
    for (int i = 0; i < 256; ++i) acc = fmaf(wr[i], Vin[i * MM + m], acc);
    out[idx] = acc;
}

// ---------- fused Smat row + softmax ----------
__global__ void smsm_k(const float* __restrict__ Hh, const float* __restrict__ G,
                       float* __restrict__ A2) {
    int j = blockIdx.x;
    int tid = threadIdx.x;   // 128
    __shared__ float row[96];
    __shared__ float red[128];
    for (int i = tid; i < MM; i += 128) {
        float acc = 0.f;
        for (int c = 0; c < 256; ++c) acc = fmaf(Hh[c * MM + j], G[c * MM + i], acc);
        row[i] = acc;
    }
    __syncthreads();
    float val = (tid < MM) ? row[tid] : -INFINITY;
    red[tid] = val; __syncthreads();
    for (int s = 64; s > 0; s >>= 1) {
        if (tid < s) red[tid] = fmaxf(red[tid], red[tid + s]);
        __syncthreads();
    }
    float mx = red[0]; __syncthreads();
    float e = (tid < MM) ? expf(val - mx) : 0.f;
    red[tid] = e; __syncthreads();
    for (int s = 64; s > 0; s >>= 1) {
        if (tid < s) red[tid] += red[tid + s];
        __syncthreads();
    }
    float inv = 1.f / red[0];
    if (tid < MM) A2[j * MM + tid] = e * inv;
}

__global__ void t1_k(const float* __restrict__ V1, const float* __restrict__ wc1,
                     float* __restrict__ t1) {
    int idx = blockIdx.x * 256 + threadIdx.x;
    if (idx >= MM * 384) return;
    int c = idx % 384, m = idx / 384;
    float acc = 0.f;
    for (int d = 0; d < 256; ++d) acc = fmaf(V1[d * MM + m], wc1[d * 384 + c], acc);
    t1[idx] = acc;
}

__global__ void c1_k(const float* __restrict__ A2, const float* __restrict__ t1,
                     const float* __restrict__ bc1, float* __restrict__ c1) {
    int idx = blockIdx.x * 256 + threadIdx.x;
    if (idx >= MM * 384) return;
    int c = idx % 384, j = idx / 384;
    float acc = bc1[c];
    for (int i = 0; i < MM; ++i) acc = fmaf(A2[j * MM + i], t1[i * 384 + c], acc);
    c1[idx] = lrelu(acc);
}

__global__ void t2_k(const float* __restrict__ c1, const float* __restrict__ wc2,
                     float* __restrict__ t2) {
    int idx = blockIdx.x * 256 + threadIdx.x;
    if (idx >= MM * 256) return;
    int c = idx % 256, m = idx / 256;
    const float* cr = c1 + m * 384;
    float acc = 0.f;
    for (int d = 0; d < 384; ++d) acc = fmaf(cr[d], wc2[d * 256 + c], acc);
    t2[idx] = acc;
}

__global__ void v2_k(const float* __restrict__ A2, const float* __restrict__ t2,
                     const float* __restrict__ bc2, float* __restrict__ V2m) {
    int idx = blockIdx.x * 256 + threadIdx.x;
    if (idx >= MM * 256) return;
    int c = idx % 256, j = idx / 256;
    float acc = bc2[c];
    for (int i = 0; i < MM; ++i) acc = fmaf(A2[j * MM + i], t2[i * 256 + c], acc);
    V2m[idx] = lrelu(acc);
}

__global__ void final_k(const float* __restrict__ Xf2, const float* __restrict__ V2m,
                        float* __restrict__ out) {
    __shared__ float red[256];
    float acc = 0.f;
    for (int idx = threadIdx.x; idx < DD * MM; idx += 256)
        acc = fmaf(Xf2[idx], V2m[idx], acc);
    red[threadIdx.x] = acc; __syncthreads();
    for (int s = 128; s > 0; s >>= 1) {
        if (threadIdx.x < s) red[threadIdx.x] += red[threadIdx.x + s];
        __syncthreads();
    }
    if (threadIdx.x == 0) out[0] = red[0];
}

extern "C" void kernel_launch(void* const* d_in, const int* in_sizes, int n_in,
                              void* d_out, int out_size, void* d_ws, size_t ws_size,
                              hipStream_t stream) {
    const float* search = (const float*)d_in[0];
    const float* exemp  = (const float*)d_in[1];
    const float* aw1 = (const float*)d_in[2];  const float* ab1 = (const float*)d_in[3];
    const float* aw2 = (const float*)d_in[4];  const float* ab2 = (const float*)d_in[5];
    const float* aw3 = (const float*)d_in[6];  const float* ab3 = (const float*)d_in[7];
    const float* aw4 = (const float*)d_in[8];  const float* ab4 = (const float*)d_in[9];
    const float* aw5 = (const float*)d_in[10]; const float* ab5 = (const float*)d_in[11];
    const float* wcd = (const float*)d_in[12]; const float* bcd = (const float*)d_in[13];
    const float* wt  = (const float*)d_in[14]; const float* bt  = (const float*)d_in[15];
    const float* ws1 = (const float*)d_in[16]; const float* bs1 = (const float*)d_in[17];
    const float* ws2 = (const float*)d_in[18]; const float* bs2 = (const float*)d_in[19];
    const float* wg  = (const float*)d_in[20]; const float* bg  = (const float*)d_in[21];
    const float* wh  = (const float*)d_in[22]; const float* bh  = (const float*)d_in[23];
    const float* wc1 = (const float*)d_in[24]; const float* bc1 = (const float*)d_in[25];
    const float* wc2 = (const float*)d_in[26]; const float* bc2 = (const float*)d_in[27];

    float* ws = (float*)d_ws;
    float* R1 = ws;
    float* R2 = ws + 3870720;
    float* R3 = ws + 7544832;
    float* Wg = ws + 8628864;

    ushort_t* in1p  = (ushort_t*)R1;
    ushort_t* c1out = (ushort_t*)R2;
    ushort_t* p1out = (ushort_t*)R3;
    ushort_t* c2out = (ushort_t*)R1;
    ushort_t* p2out = (ushort_t*)R2;
    ushort_t* c3out = (ushort_t*)(R2 + 775200);
    ushort_t* c4out = (ushort_t*)R1;
    ushort_t* c5out = (ushort_t*)R3;
    ushort_t* WT    = (ushort_t*)Wg;

    // ---- conv stack: exact v5 geometry (547us-verified) ----
    zfill_k<<<(965500 + 255) / 256, 256, 0, stream>>>((float4*)R1, 965500);
    prep1_k<<<(BATCH * H0 * W0 + 255) / 256, 256, 0, stream>>>(search, exemp, in1p);
    wprep_k<<<(4608 + 255) / 256, 256, 0, stream>>>(aw1, WT, 11, 12, 11, 4, 3, 18, 4608, 64);
    conv_mfma13<4, false><<<dim3(106, 1, BATCH), 256, 0, stream>>>(
        in1p, WT, ab1, c1out, HP1, WP1, 4, W1, H1 * W1, 9, 12, H1, W1, 0, 64);
    zfill_k<<<(270504 + 255) / 256, 256, 0, stream>>>((float4*)R3, 270504);
    pool_nhwc<<<(BATCH * 64 * H1P * W1P + 255) / 256, 256, 0, stream>>>(
        c1out, p1out, 64, H1, W1, H1P, W1P, 51, 39, 2);
    wprep_k<<<(38400 + 255) / 256, 256, 0, stream>>>(aw2, WT, 5, 5, 5, 64, 64, 50, 38400, 192);
    conv_mfma13<1, true><<<dim3(26, 3, BATCH), 256, 0, stream>>>(
        p1out, WT, ab2, c2out, 51, 39, 64, W1P, H1P * W1P, 25, 5, H1P, W1P, 0, 192);
    zfill_k<<<(581400 + 255) / 256, 256, 0, stream>>>((float4*)R2, 581400);
    pool_nhwc<<<(BATCH * 192 * H2P * W2P + 255) / 256, 256, 0, stream>>>(
        c2out, p2out, 192, H1P, W1P, H2P, W2P, 25, 19, 1);
    wprep_k<<<(82944 + 255) / 256, 256, 0, stream>>>(aw3, WT, 3, 3, 3, 192, 192, 54, 82944, 384);
    conv_mfma13<1, true><<<dim3(7, 6, BATCH), 256, 0, stream>>>(
        p2out, WT, ab3, c3out, 25, 19, 192, W2P, H2P * W2P, 27, 3, 25, 19, 1, 384);
    zfill_k<<<(258400 + 255) / 256, 256, 0, stream>>>((float4*)R1, 258400);
    wprep_k<<<(110592 + 255) / 256, 256, 0, stream>>>(aw4, WT, 3, 3, 3, 384, 384, 108, 110592, 256);
    conv_mfma13<1, true><<<dim3(7, 4, BATCH), 256, 0, stream>>>(
        c3out, WT, ab4, c4out, 25, 19, 384, W2P, H2P * W2P, 54, 3, 25, 19, 1, 256);
    wprep_k<<<(73728 + 255) / 256, 256, 0, stream>>>(aw5, WT, 3, 3, 3, 256, 256, 72, 73728, 256);
    conv_mfma13<1, true><<<dim3(7, 4, BATCH), 256, 0, stream>>>(
        c4out, WT, ab5, c5out, 25, 19, 256, W2P, H2P * W2P, 36, 3, H2P, W2P, 0, 256);

    // ---- tail region layout in R1 ----
    float*    P      = R1 + 2417664;
    ushort_t* PB     = (ushort_t*)(R1 + 2800640);
    ushort_t* XfPad  = (ushort_t*)(R1 + 2992128);   // rows 0 & 89 zeroed by first R1 zfill
    float*    xc     = R1 + 3003648;

    ushort_t* WS1T = (ushort_t*)Wg;
    ushort_t* WS2T = (ushort_t*)(Wg + 65536);
    ushort_t* WCDT = (ushort_t*)(Wg + 131072);
    wprep_gemm_k<<<(57344 + 255) / 256, 256, 0, stream>>>(ws1, ws2, wcd, WS1T, WS2T, WCDT);

    pool5_k<<<(BATCH * 256 * MM + 255) / 256, 256, 0, stream>>>(c5out, P, PB, XfPad);
    float* Xf2 = P;

    float* xhat = R1 + 1024;
    float* Y1   = R1 + 23552;
    ushort_t* h1b = (ushort_t*)(R1 + 752640);
    float* Y2   = R1 + 1473536;
    float* h2   = R1 + 1838080;
    float* V1   = R1 + 2198528;
    float* Vx   = R1 + 2221056;
    float* G    = R1 + 2243584;
    float* Hh   = R1 + 2266112;
    float* A2   = R1 + 2296832;
    float* t1   = R1 + 2305024;
    float* c1   = R1 + 2338816;
    float* t2   = R1 + 2372608;
    float* V2m  = R1 + 2395136;

    gemm_mfma3<0, true, false><<<dim3(2, 4), 256, 0, stream>>>(
        XfPad, WCDT, bcd, xc, 256, MM, 24, 1, MM);
    xhat2_k<<<(DD * MM + 255) / 256, 256, 0, stream>>>(xc, wt, bt, xhat);

    gemm_mfma3<1, false, true><<<dim3(22, 8), 256, 0, stream>>>(
        PB, WS1T, nullptr, Y1, 256, TM, 8, 512, 1);
    sh1_k<<<(T_EX * 512 + 255) / 256, 256, 0, stream>>>(Y1, bs1, h1b);
    gemm_mfma3<0, false, true><<<dim3(22, 4), 256, 0, stream>>>(
        h1b, WS2T, nullptr, Y2, 512, TM, 16, 256, 1);
    sh2_k<<<(T_EX * 256 + 255) / 256, 256, 0, stream>>>(Y2, bs2, h2);
    v1vx_k<<<(DD * MM + 255) / 256, 256, 0, stream>>>(h2, xhat, V1, Vx);

    lin88_k<<<dim3((DD * MM + 255) / 256, 2), 256, 0, stream>>>(wg, bg, wh, bh, Vx, G, Hh);
    smsm_k<<<MM, 128, 0, stream>>>(Hh, G, A2);

    t1_k<<<(MM * 384 + 255) / 256, 256, 0, stream>>>(V1, wc1, t1);
    c1_k<<<(MM * 384 + 255) / 256, 256, 0, stream>>>(A2, t1, bc1, c1);
    t2_k<<<(MM * 256 + 255) / 256, 256, 0, stream>>>(c1, wc2, t2);
    v2_k<<<(MM * 256 + 255) / 256, 256, 0, stream>>>(A2, t2, bc2, V2m);

    final_k<<<1, 256, 0, stream>>>(Xf2, V2m, (float*)d_out);
}

// Round 8
// 477.206 us; speedup vs baseline: 1.2709x; 1.1488x over previous
//
#include <hip/hip_runtime.h>
#include <hip/hip_bf16.h>
#include <math.h>

// ---------- dims ----------
#define BATCH 17
#define T_EX 16
#define H0 383
#define W0 287
#define C1 64
#define H1 95
#define W1 71
#define H1P 47
#define W1P 35
#define C2 192
#define H2P 23
#define W2P 17
#define C3 384
#define C45 256
#define H5P 11
#define W5P 8
#define DD 256
#define MM 88
#define TM 1408

#define HP1 389
#define WP1 292

typedef unsigned short ushort_t;
typedef __attribute__((ext_vector_type(8))) short short8;
typedef __attribute__((ext_vector_type(4))) float f32x4;

__device__ __forceinline__ float lrelu(float v) { return v > 0.f ? v : 0.01f * v; }

__device__ __forceinline__ ushort_t f2bf(float f) {
    unsigned int u = __float_as_uint(f);
    unsigned int r = (u + 0x7fffu + ((u >> 16) & 1u)) >> 16;
    return (ushort_t)r;
}
__device__ __forceinline__ float b2f(ushort_t b) {
    return __uint_as_float(((unsigned int)b) << 16);
}
__device__ __forceinline__ short8 ld16(const ushort_t* p) { return *(const short8*)p; }
__device__ __forceinline__ short8 ld2x8(const ushort_t* p) {
    union { uint2 u[2]; short8 s; } uu;
    uu.u[0] = *(const uint2*)p;
    uu.u[1] = *(const uint2*)(p + 4);
    return uu.s;
}
// async global -> LDS, 16B per lane; LDS dest = wave-uniform base + lane*16
__device__ __forceinline__ void async_cp16(ushort_t* l, const ushort_t* g) {
    __builtin_amdgcn_global_load_lds(
        (const __attribute__((address_space(1))) void*)g,
        (__attribute__((address_space(3))) void*)l, 16, 0, 0);
}

// ---------- conv1 input prep, FUSED with pad-zeroing (replaces zfill+prep1):
// writes EVERY cell of in1p: pad -> 0, interior -> bf16 data. Byte-identical
// to the old zfill-then-prep1 sequence. ----------
__global__ void prep1f_k(const float* __restrict__ search, const float* __restrict__ exemp,
                         ushort_t* __restrict__ out) {
    int idx = blockIdx.x * 256 + threadIdx.x;
    if (idx >= BATCH * HP1 * WP1) return;
    int x = idx % WP1; int t = idx / WP1;
    int y = t % HP1; int b = t / HP1;
    ushort4 o = {0, 0, 0, 0};
    int ix = x - 2, iy = y - 2;
    if (ix >= 0 && ix < W0 && iy >= 0 && iy < H0) {
        const float* src = (b == 0) ? search : exemp + (size_t)(b - 1) * 3 * H0 * W0;
        const int hw = H0 * W0;
        o.x = f2bf(src[iy * W0 + ix]);
        o.y = f2bf(src[hw + iy * W0 + ix]);
        o.z = f2bf(src[2 * hw + iy * W0 + ix]);
    }
    *(ushort4*)&out[(size_t)idx * 4] = o;
}

// ---------- conv weight prep (+ optional trailing zero-fill region) ----------
__global__ void wprep_k(const float* __restrict__ w, ushort_t* __restrict__ out,
                        int KH, int KWl, int KWr, int CINl, int CINr,
                        int NKS, int nch, int OCr,
                        float4* __restrict__ zp, int zn4) {
    const int wb = (nch + 255) >> 8;
    if ((int)blockIdx.x >= wb) {
        int z = (blockIdx.x - wb) * 256 + threadIdx.x;
        if (z < zn4) zp[z] = (float4){0.f, 0.f, 0.f, 0.f};
        return;
    }
    int idx = blockIdx.x * 256 + threadIdx.x;
    if (idx >= nch) return;
    int c = idx & 255;
    int rest = idx >> 8;
    int ks = rest % NKS;
    int ocb = rest / NKS;
    int k8 = c >> 6, m = c & 63;
    int oc = ocb * 64 + m;
    int KWC = KWl * CINl;
    ushort_t* o = out + (size_t)idx * 8;
#pragma unroll
    for (int j = 0; j < 8; ++j) {
        int kg = ks * 32 + k8 * 8 + j;
        int ky = kg / KWC; int rem = kg - ky * KWC;
        int kx = rem / CINl; int ic = rem - kx * CINl;
        float v = 0.f;
        if (oc < OCr && ky < KH && kx < KWr && ic < CINr)
            v = w[(((size_t)oc * CINr + ic) * KH + ky) * KWr + kx];
        o[j] = f2bf(v);
    }
}

// ====================================================================
// bf16 MFMA implicit-GEMM conv, v14 = v13 (49us-verified) +
//  - 2x2 wave grid (wave = 32oc x 32px): per-wave LDS reads 10KB->8KB
//    per step, block B-read redundancy 4x->2x (~20% LDS-port cut).
//  - batch-flattened N (2D grid): no per-batch pixel waste.
//  Staging (A DMA + swizzled px-major B, proven conflict-free in r7),
//  barriers, K-order, accumulation order: UNCHANGED -> bitwise-identical.
// ====================================================================
template <int STRIDE, bool A16>
__global__ __launch_bounds__(256) void conv_mfma14(
    const ushort_t* __restrict__ inp, const ushort_t* __restrict__ wt,
    const float* __restrict__ bias, ushort_t* __restrict__ out,
    int Hp, int Wp, int C, int Wout, int HW, int Ntot, int NKS2, int KWl,
    int OHp, int OWp, int OPAD, int COUT) {
    const int tid = threadIdx.x;
    const int wv = tid >> 6, lane = tid & 63;
    const int quad = lane >> 4, l16 = lane & 15;
    const int wr = wv >> 1, wc = wv & 1;     // 2x2 wave grid: (oc-half, px-half)
    const int n_blk = blockIdx.x * 64;
    const int ocb = blockIdx.y;

    __shared__ ushort_t As[2][4096];   // [buf][h:2][k8:4][oc:64][8] = 8 KB/buf
    __shared__ ushort_t Bs[2][4096];   // [buf][kg:8][px-swz:64][8] = 8 KB/buf
    __shared__ int offs[432];

    const int KWC = KWl * C;
    for (int g = tid; g < NKS2 * 8; g += 256) {
        int kg = g * 8;
        int ky = kg / KWC; int rem = kg - ky * KWC;
        int kx = rem / C; int c8 = rem - kx * C;
        offs[g] = (ky * Wp + kx) * C + c8;
    }

    const size_t HWC = (size_t)Hp * Wp * C;

    // staging roles
    const int g8 = lane & 7, po = lane >> 3;
    const ushort_t* bsrc0 = nullptr; const ushort_t* bsrc1 = nullptr;
    const ushort_t* lsrc = nullptr;
    int ws0 = 0, ws1 = 0;
    if constexpr (A16) {
        // px-major coalesced: lane (g8,po) loads px {wv*16+po, wv*16+8+po}, k-group g8
        int np0 = n_blk + wv * 16 + po;      if (np0 >= Ntot) np0 = Ntot - 1;
        int np1 = n_blk + wv * 16 + 8 + po;  if (np1 >= Ntot) np1 = Ntot - 1;
        int b0 = np0 / HW, p0 = np0 - b0 * HW;
        int b1 = np1 / HW, p1 = np1 - b1 * HW;
        int oy0 = p0 / Wout, ox0 = p0 - oy0 * Wout;
        int oy1 = p1 / Wout, ox1 = p1 - oy1 * Wout;
        bsrc0 = inp + (size_t)b0 * HWC + (size_t)(oy0 * STRIDE * Wp + ox0 * STRIDE) * C;
        bsrc1 = inp + (size_t)b1 * HWC + (size_t)(oy1 * STRIDE * Wp + ox1 * STRIDE) * C;
        // conflict-free swizzle (r7-verified, conflicts==0): slot kg*512 + (px^kg)*8
        ws0 = g8 * 512 + (((wv * 16 + po) ^ g8) * 8);
        ws1 = g8 * 512 + (((wv * 16 + 8 + po) ^ g8) * 8);
    } else {
        // conv1 path (C=4, 8B-aligned taps): per-lane pixel, linear layout
        int n0 = n_blk + lane; if (n0 >= Ntot) n0 = Ntot - 1;
        int b0 = n0 / HW, p0 = n0 - b0 * HW;
        int oy = p0 / Wout, ox = p0 - oy * Wout;
        lsrc = inp + (size_t)b0 * HWC + (size_t)(oy * STRIDE * Wp + ox * STRIDE) * C;
    }

    f32x4 acc[2][2];
#pragma unroll
    for (int am = 0; am < 2; ++am)
#pragma unroll
        for (int bn = 0; bn < 2; ++bn) acc[am][bn] = (f32x4){0.f, 0.f, 0.f, 0.f};

    const ushort_t* wblk = wt + (size_t)ocb * (size_t)NKS2 * 4096;

    __syncthreads();   // offs ready

    // ---- prologue: stage step 0 into buf 0 ----
    {
        const ushort_t* aS = wblk + tid * 8;
        async_cp16(&As[0][tid * 8], aS);
        async_cp16(&As[0][2048 + tid * 8], aS + 2048);
        if constexpr (A16) {
            *(short8*)&Bs[0][ws0] = ld16(bsrc0 + offs[g8]);
            *(short8*)&Bs[0][ws1] = ld16(bsrc1 + offs[g8]);
        } else {
            const int o0 = offs[wv], o1 = offs[4 + wv];
            *(short8*)&Bs[0][tid * 8] = ld2x8(lsrc + o0);
            *(short8*)&Bs[0][2048 + tid * 8] = ld2x8(lsrc + o1);
        }
    }
    __syncthreads();

    for (int ks2 = 0; ks2 < NKS2; ++ks2) {
        const int cur = ks2 & 1, nxt = cur ^ 1;
        const bool more = (ks2 + 1 < NKS2);
        short8 rb0, rb1;
        if (more) {
            const ushort_t* aS = wblk + (size_t)(ks2 + 1) * 4096 + tid * 8;
            async_cp16(&As[nxt][tid * 8], aS);
            async_cp16(&As[nxt][2048 + tid * 8], aS + 2048);
            if constexpr (A16) {
                rb0 = ld16(bsrc0 + offs[(ks2 + 1) * 8 + g8]);
                rb1 = ld16(bsrc1 + offs[(ks2 + 1) * 8 + g8]);
            } else {
                const int o0 = offs[(ks2 + 1) * 8 + wv], o1 = offs[(ks2 + 1) * 8 + 4 + wv];
                *(short8*)&Bs[nxt][tid * 8] = ld2x8(lsrc + o0);
                *(short8*)&Bs[nxt][2048 + tid * 8] = ld2x8(lsrc + o1);
            }
        }
        // compute: 2 k-halves x (2 oc-frags x 2 px-frags) = 8 MFMA / wave
#pragma unroll
        for (int h = 0; h < 2; ++h) {
            const short8 a0 = *(const short8*)&As[cur][h * 2048 + (quad * 64 + wr * 32 + l16) * 8];
            const short8 a1 = *(const short8*)&As[cur][h * 2048 + (quad * 64 + wr * 32 + 16 + l16) * 8];
            short8 b0, b1;
            if constexpr (A16) {
                b0 = *(const short8*)&Bs[cur][h * 2048 + quad * 512 + (((wc * 32 + l16) ^ (h * 4 + quad)) * 8)];
                b1 = *(const short8*)&Bs[cur][h * 2048 + quad * 512 + (((wc * 32 + 16 + l16) ^ (h * 4 + quad)) * 8)];
            } else {
                b0 = *(const short8*)&Bs[cur][h * 2048 + (quad * 64 + wc * 32 + l16) * 8];
                b1 = *(const short8*)&Bs[cur][h * 2048 + (quad * 64 + wc * 32 + 16 + l16) * 8];
            }
            acc[0][0] = __builtin_amdgcn_mfma_f32_16x16x32_bf16(a0, b0, acc[0][0], 0, 0, 0);
            acc[0][1] = __builtin_amdgcn_mfma_f32_16x16x32_bf16(a0, b1, acc[0][1], 0, 0, 0);
            acc[1][0] = __builtin_amdgcn_mfma_f32_16x16x32_bf16(a1, b0, acc[1][0], 0, 0, 0);
            acc[1][1] = __builtin_amdgcn_mfma_f32_16x16x32_bf16(a1, b1, acc[1][1], 0, 0, 0);
        }
        if constexpr (A16) {
            if (more) {
                *(short8*)&Bs[nxt][ws0] = rb0;
                *(short8*)&Bs[nxt][ws1] = rb1;
            }
        }
        __syncthreads();
    }

    const int oc0 = ocb * 64 + wr * 32 + quad * 4;
#pragma unroll
    for (int bn = 0; bn < 2; ++bn) {
        int n = n_blk + wc * 32 + bn * 16 + l16;
        if (n < Ntot) {
            int bb = n / HW; int pix = n - bb * HW;
            int y = pix / Wout, x = pix - y * Wout;
            size_t base = (((size_t)bb * OHp + y + OPAD) * OWp + x + OPAD) * COUT;
#pragma unroll
            for (int am = 0; am < 2; ++am) {
                const int oc = oc0 + am * 16;
                ushort4 o;
                o.x = f2bf(fmaxf(acc[am][bn][0] + bias[oc], 0.f));
                o.y = f2bf(fmaxf(acc[am][bn][1] + bias[oc + 1], 0.f));
                o.z = f2bf(fmaxf(acc[am][bn][2] + bias[oc + 2], 0.f));
                o.w = f2bf(fmaxf(acc[am][bn][3] + bias[oc + 3], 0.f));
                *(ushort4*)&out[base + oc] = o;
            }
        }
    }
}

// ====================================================================
// Generic bf16 MFMA GEMM body (device fn): A direct from global (tiled),
// B LDS dbuf. Wrapped by single- and paired-launch kernels.
// ====================================================================
template <int MODE, bool HASBIAS, bool SC1>
__device__ __forceinline__ void gemm_dev(
    ushort_t (*Bs)[2048],
    const ushort_t* __restrict__ Bsrc, const ushort_t* __restrict__ wt,
    const float* __restrict__ bias, float* __restrict__ out,
    int RS, int N, int NKS, int sn, int sc, int bx, int by) {
    const int tid = threadIdx.x;
    const int wv = tid >> 6, lane = tid & 63;
    const int quad = lane >> 4, l16 = lane & 15;
    const int n_blk = bx * 64;
    const int ocb = by;

    int n_g = n_blk + lane;
    int n_gc = n_g < N ? n_g : N - 1;
    int row = (MODE == 1) ? (1 + (n_gc & 15)) * MM + (n_gc >> 4) : n_gc;
    const size_t base0 = (size_t)row * RS;

    f32x4 acc[4];
#pragma unroll
    for (int cn = 0; cn < 4; ++cn) acc[cn] = (f32x4){0.f, 0.f, 0.f, 0.f};

    const ushort_t* wblk = wt + (size_t)ocb * NKS * 2048;
    const int afrag = (quad * 64 + wv * 16 + l16) * 8;

    short8 a0 = ld16(wblk + afrag);
    *(short8*)&Bs[0][tid * 8] = ld16(Bsrc + base0 + wv * 8);
    __syncthreads();

    for (int ks = 0; ks < NKS; ++ks) {
        const int cur = ks & 1, nxt = cur ^ 1;
        short8 a1, bn;
        const bool more = (ks + 1 < NKS);
        if (more) {
            a1 = ld16(wblk + (ks + 1) * 2048 + afrag);
            bn = ld16(Bsrc + base0 + (ks + 1) * 32 + wv * 8);
        }
#pragma unroll
        for (int cn = 0; cn < 4; ++cn) {
            const short8 bfr = *(const short8*)&Bs[cur][(quad * 64 + cn * 16 + l16) * 8];
            acc[cn] = __builtin_amdgcn_mfma_f32_16x16x32_bf16(a0, bfr, acc[cn], 0, 0, 0);
        }
        if (more) *(short8*)&Bs[nxt][tid * 8] = bn;
        a0 = a1;
        __syncthreads();
    }

    const int oc0 = ocb * 64 + wv * 16 + quad * 4;
    float bb[4] = {0.f, 0.f, 0.f, 0.f};
    if (HASBIAS) { bb[0] = bias[oc0]; bb[1] = bias[oc0+1]; bb[2] = bias[oc0+2]; bb[3] = bias[oc0+3]; }
#pragma unroll
    for (int cn = 0; cn < 4; ++cn) {
        int n = n_blk + cn * 16 + l16;
        if (n < N) {
            if (SC1) {
                float4 o;
                o.x = acc[cn][0] + bb[0]; o.y = acc[cn][1] + bb[1];
                o.z = acc[cn][2] + bb[2]; o.w = acc[cn][3] + bb[3];
                *(float4*)&out[(size_t)n * sn + oc0] = o;
            } else {
#pragma unroll
                for (int reg = 0; reg < 4; ++reg)
                    out[(size_t)n * sn + (size_t)(oc0 + reg) * sc] = acc[cn][reg] + bb[reg];
            }
        }
    }
}

template <int MODE, bool HASBIAS, bool SC1>
__global__ __launch_bounds__(256) void gemm_mfma3_k(
    const ushort_t* __restrict__ Bsrc, const ushort_t* __restrict__ wt,
    const float* __restrict__ bias, float* __restrict__ out,
    int RS, int N, int NKS, int sn, int sc) {
    __shared__ ushort_t Bs[2][2048];
    gemm_dev<MODE, HASBIAS, SC1>(Bs, Bsrc, wt, bias, out, RS, N, NKS, sn, sc,
                                 blockIdx.x, blockIdx.y);
}

// merged launch: xc-gemm (2x4 blocks) + Y1-gemm (22x8 blocks); grid (24,8)
__global__ __launch_bounds__(256) void gemm_pair_k(
    const ushort_t* __restrict__ XfPad, const ushort_t* __restrict__ WCDT,
    const float* __restrict__ bcd, float* __restrict__ xc,
    const ushort_t* __restrict__ PB, const ushort_t* __restrict__ WS1T,
    float* __restrict__ Y1) {
    __shared__ ushort_t Bs[2][2048];
    if (blockIdx.x < 2) {
        if (blockIdx.y < 4)
            gemm_dev<0, true, false>(Bs, XfPad, WCDT, bcd, xc, 256, MM, 24, 1, MM,
                                     blockIdx.x, blockIdx.y);
    } else {
        gemm_dev<1, false, true>(Bs, PB, WS1T, nullptr, Y1, 256, TM, 8, 512, 1,
                                 blockIdx.x - 2, blockIdx.y);
    }
}

// ---------- maxpool k3 s2 VALID, NHWC bf16, FUSED pad-zeroing +
// optional trailing zero region (replaces zfill+pool) ----------
__global__ void pool_p_k(const ushort_t* __restrict__ in, ushort_t* __restrict__ out,
                         int C, int Hin, int Win, int Hout, int Wout,
                         int OHp, int OWp, int OPAD,
                         float4* __restrict__ zp, int zn4) {
    const int total = BATCH * C * OHp * OWp;
    const int pb = (total + 255) >> 8;
    if ((int)blockIdx.x >= pb) {
        int z = (blockIdx.x - pb) * 256 + threadIdx.x;
        if (z < zn4) zp[z] = (float4){0.f, 0.f, 0.f, 0.f};
        return;
    }
    int idx = blockIdx.x * 256 + threadIdx.x;
    if (idx >= total) return;
    int c = idx % C; int r = idx / C;
    int x = r % OWp; r /= OWp;
    int y = r % OHp; int b = r / OHp;
    int iy = y - OPAD, ix = x - OPAD;
    ushort_t v = 0;
    if (iy >= 0 && iy < Hout && ix >= 0 && ix < Wout) {
        const int rs = Win * C;
        const ushort_t* p = in + (((size_t)b * Hin + 2 * iy) * Win + 2 * ix) * C + c;
        float m = b2f(p[0]);
        m = fmaxf(m, b2f(p[C])); m = fmaxf(m, b2f(p[2 * C]));
        m = fmaxf(m, b2f(p[rs])); m = fmaxf(m, b2f(p[rs + C])); m = fmaxf(m, b2f(p[rs + 2 * C]));
        m = fmaxf(m, b2f(p[2 * rs])); m = fmaxf(m, b2f(p[2 * rs + C])); m = fmaxf(m, b2f(p[2 * rs + 2 * C]));
        v = f2bf(m);
    }
    out[idx] = v;   // idx enumerates (((b*OHp+y)*OWp+x)*C+c) exactly
}

// ---------- merged: gemm weight prep (ws1|ws2|wcd) + pool5 ----------
__global__ void wg_pool5_k(const float* __restrict__ ws1, const float* __restrict__ ws2,
                           const float* __restrict__ wcd, ushort_t* __restrict__ WS1T,
                           ushort_t* __restrict__ WS2T, ushort_t* __restrict__ WCDT,
                           const ushort_t* __restrict__ in, float* __restrict__ P,
                           ushort_t* __restrict__ PB, ushort_t* __restrict__ XfPad) {
    if (blockIdx.x < 224) {
        int idx = blockIdx.x * 256 + threadIdx.x;
        const float* src; ushort_t* dst; int NKS, mode = 0, sa = 1, sk = 0, base;
        if (idx < 16384)       { src = ws1; dst = WS1T; NKS = 8;  sk = 512; base = idx; }
        else if (idx < 32768)  { src = ws2; dst = WS2T; NKS = 16; sk = 256; base = idx - 16384; }
        else                   { src = wcd; dst = WCDT; NKS = 24; mode = 1; base = idx - 32768; }
        int c = base & 255;
        int rest = base >> 8;
        int ks = rest % NKS;
        int ocb = rest / NKS;
        int k8 = c >> 6, m = c & 63;
        int oc = ocb * 64 + m;
        ushort_t* o = dst + (size_t)base * 8;
#pragma unroll
        for (int j = 0; j < 8; ++j) {
            int kg = ks * 32 + k8 * 8 + j;
            float v;
            if (mode == 0) v = src[(size_t)oc * sa + (size_t)kg * sk];
            else           v = src[(size_t)oc * 768 + (kg & 255) * 3 + (kg >> 8)];
            o[j] = f2bf(v);
        }
    } else {
        int idx = (blockIdx.x - 224) * 256 + threadIdx.x;
        if (idx >= BATCH * 256 * MM) return;
        int c = idx % 256; int r = idx / 256;
        int x = r % W5P; r /= W5P;
        int y = r % H5P; int b = r / H5P;
        const int rs = W2P * 256;
        const ushort_t* p = in + (((size_t)b * H2P + 2 * y) * W2P + 2 * x) * 256 + c;
        float m = b2f(p[0]);
        m = fmaxf(m, b2f(p[256])); m = fmaxf(m, b2f(p[512]));
        m = fmaxf(m, b2f(p[rs])); m = fmaxf(m, b2f(p[rs + 256])); m = fmaxf(m, b2f(p[rs + 512]));
        m = fmaxf(m, b2f(p[2 * rs])); m = fmaxf(m, b2f(p[2 * rs + 256])); m = fmaxf(m, b2f(p[2 * rs + 512]));
        int mm = y * W5P + x;
        size_t o = ((size_t)b * MM + mm) * 256 + c;
        P[o] = m;
        ushort_t mb = f2bf(m);
        PB[o] = mb;
        if (b == 0) XfPad[(size_t)(mm + 1) * 256 + c] = mb;
    }
}

// ---------- merged: xhat (with in-block vmax) + sh1 ----------
__global__ void xhat_sh1_k(const float* __restrict__ xc, const float* __restrict__ wt,
                           const float* __restrict__ bt, float* __restrict__ xhat,
                           const float* __restrict__ Y1, const float* __restrict__ bs1,
                           ushort_t* __restrict__ h1b) {
    if (blockIdx.x < 88) {
        __shared__ float lv[256];
        {
            int j = threadIdx.x;
            const float* xr = xc + (size_t)j * MM;
            float mx = xr[0];
            for (int k = 1; k < MM; ++k) mx = fmaxf(mx, xr[k]);
            lv[j] = mx;
        }
        __syncthreads();
        int idx = blockIdx.x * 256 + threadIdx.x;
        if (idx >= DD * MM) return;
        int k = idx % MM, o = idx / MM;
        float acc = bt[o];
        for (int i = 0; i < 256; ++i) acc = fmaf(lv[i], wt[(i * 256 + o) * MM + k], acc);
        xhat[idx] = acc;
    } else {
        int idx = (blockIdx.x - 88) * 256 + threadIdx.x;
        if (idx >= T_EX * 512) return;
        int c = idx & 511, t = idx >> 9;
        float s = 0.f;
        for (int m = 0; m < MM; ++m) s += Y1[(size_t)(m * T_EX + t) * 512 + c];
        float base = s + bs1[c];
        if (t == 0) {
            for (int m = 0; m < MM; ++m) {
                float val = base - Y1[(size_t)(m * T_EX) * 512 + c];
                h1b[(size_t)(m * T_EX) * 512 + c] = f2bf(lrelu(val));
            }
        } else {
            ushort_t v = f2bf(lrelu(base));
            for (int m = 0; m < MM; ++m)
                h1b[(size_t)(m * T_EX + t) * 512 + c] = v;
        }
    }
}

// ---------- fused s2+h2 ----------
__global__ void sh2_k(const float* __restrict__ Y2, const float* __restrict__ bs2,
                      float* __restrict__ h2) {
    int idx = blockIdx.x * 256 + threadIdx.x;
    if (idx >= T_EX * 256) return;
    int c = idx & 255, t = idx >> 8;
    float s = 0.f;
    for (int m = 0; m < MM; ++m) s += Y2[(size_t)(m * T_EX + t) * 256 + c];
    float base = s + bs2[c];
    if (t == 0) {
        for (int m = 0; m < MM; ++m)
            h2[(size_t)(m * T_EX) * 256 + c] = lrelu(base - Y2[(size_t)(m * T_EX) * 256 + c]);
    } else {
        float v = lrelu(base);
        for (int m = 0; m < MM; ++m) h2[(size_t)(m * T_EX + t) * 256 + c] = v;
    }
}

__global__ void v1vx_k(const float* __restrict__ h2, const float* __restrict__ xhat,
                       float* __restrict__ V1, float* __restrict__ Vx) {
    int idx = blockIdx.x * 256 + threadIdx.x;
    if (idx >= DD * MM) return;
    int m = idx % MM, d = idx / MM;
    float mx = -INFINITY;
    for (int t = 0; t < T_EX; ++t) mx = fmaxf(mx, h2[(m * T_EX + t) * 256 + d]);
    V1[idx] = mx;
    Vx[idx] = mx + xhat[idx];
}

// ---------- merged: lin88 (g & h) + t1 ----------
__global__ void lin_t1_k(const float* __restrict__ Wgm, const float* __restrict__ bg,
                         const float* __restrict__ Whm, const float* __restrict__ bh,
                         const float* __restrict__ Vx, float* __restrict__ G,
                         float* __restrict__ Hh,
                         const float* __restrict__ V1, const float* __restrict__ wc1,
                         float* __restrict__ t1) {
    int bx = blockIdx.x;
    if (bx < 176) {
        int sel = bx >= 88;
        int idx = (bx - (sel ? 88 : 0)) * 256 + threadIdx.x;
        if (idx >= DD * MM) return;
        const float* W = sel ? Whm : Wgm;
        const float* bias = sel ? bh : bg;
        float* out = sel ? Hh : G;
        int m = idx % MM, o = idx / MM;
        const float* wr = W + o * 256;
        float acc = bias[o];
        for (int i = 0; i < 256; ++i) acc = fmaf(wr[i], Vx[i * MM + m], acc);
        out[idx] = acc;
    } else {
        int idx = (bx - 176) * 256 + threadIdx.x;
        if (idx >= MM * 384) return;
        int c = idx % 384, m = idx / 384;
        float acc = 0.f;
        for (int d = 0; d < 256; ++d) acc = fmaf(V1[d * MM + m], wc1[d * 384 + c], acc);
        t1[idx] = acc;
    }
}

// ---------- fused Smat row + softmax ----------
__global__ void smsm_k(const float* __restrict__ Hh, const float* __restrict__ G,
                       float* __restrict__ A2) {
    int j = blockIdx.x;
    int tid = threadIdx.x;   // 128
    __shared__ float row[96];
    __shared__ float red[128];
    for (int i = tid; i < MM; i += 128) {
        float acc = 0.f;
        for (int c = 0; c < 256; ++c) acc = fmaf(Hh[c * MM + j], G[c * MM + i], acc);
        row[i] = acc;
    }
    __syncthreads();
    float val = (tid < MM) ? row[tid] : -INFINITY;
    red[tid] = val; __syncthreads();
    for (int s = 64; s > 0; s >>= 1) {
        if (tid < s) red[tid] = fmaxf(red[tid], red[tid + s]);
        __syncthreads();
    }
    float mx = red[0]; __syncthreads();
    float e = (tid < MM) ? expf(val - mx) : 0.f;
    red[tid] = e; __syncthreads();
    for (int s = 64; s > 0; s >>= 1) {
        if (tid < s) red[tid] += red[tid + s];
        __syncthreads();
    }
    float inv = 1.f / red[0];
    if (tid < MM) A2[j * MM + tid] = e * inv;
}

__global__ void c1_k(const float* __restrict__ A2, const float* __restrict__ t1,
                     const float* __restrict__ bc1, float* __restrict__ c1) {
    int idx = blockIdx.x * 256 + threadIdx.x;
    if (idx >= MM * 384) return;
    int c = idx % 384, j = idx / 384;
    float acc = bc1[c];
    for (int i = 0; i < MM; ++i) acc = fmaf(A2[j * MM + i], t1[i * 384 + c], acc);
    c1[idx] = lrelu(acc);
}

__global__ void t2_k(const float* __restrict__ c1, const float* __restrict__ wc2,
                     float* __restrict__ t2) {
    int idx = blockIdx.x * 256 + threadIdx.x;
    if (idx >= MM * 256) return;
    int c = idx % 256, m = idx / 256;
    const float* cr = c1 + m * 384;
    float acc = 0.f;
    for (int d = 0; d < 384; ++d) acc = fmaf(cr[d], wc2[d * 256 + c], acc);
    t2[idx] = acc;
}

__global__ void v2_k(const float* __restrict__ A2, const float* __restrict__ t2,
                     const float* __restrict__ bc2, float* __restrict__ V2m) {
    int idx = blockIdx.x * 256 + threadIdx.x;
    if (idx >= MM * 256) return;
    int c = idx % 256, j = idx / 256;
    float acc = bc2[c];
    for (int i = 0; i < MM; ++i) acc = fmaf(A2[j * MM + i], t2[i * 256 + c], acc);
    V2m[idx] = lrelu(acc);
}

__global__ void final_k(const float* __restrict__ Xf2, const float* __restrict__ V2m,
                        float* __restrict__ out) {
    __shared__ float red[256];
    float acc = 0.f;
    for (int idx = threadIdx.x; idx < DD * MM; idx += 256)
        acc = fmaf(Xf2[idx], V2m[idx], acc);
    red[threadIdx.x] = acc; __syncthreads();
    for (int s = 128; s > 0; s >>= 1) {
        if (threadIdx.x < s) red[threadIdx.x] += red[threadIdx.x + s];
        __syncthreads();
    }
    if (threadIdx.x == 0) out[0] = red[0];
}

extern "C" void kernel_launch(void* const* d_in, const int* in_sizes, int n_in,
                              void* d_out, int out_size, void* d_ws, size_t ws_size,
                              hipStream_t stream) {
    const float* search = (const float*)d_in[0];
    const float* exemp  = (const float*)d_in[1];
    const float* aw1 = (const float*)d_in[2];  const float* ab1 = (const float*)d_in[3];
    const float* aw2 = (const float*)d_in[4];  const float* ab2 = (const float*)d_in[5];
    const float* aw3 = (const float*)d_in[6];  const float* ab3 = (const float*)d_in[7];
    const float* aw4 = (const float*)d_in[8];  const float* ab4 = (const float*)d_in[9];
    const float* aw5 = (const float*)d_in[10]; const float* ab5 = (const float*)d_in[11];
    const float* wcd = (const float*)d_in[12]; const float* bcd = (const float*)d_in[13];
    const float* wt  = (const float*)d_in[14]; const float* bt  = (const float*)d_in[15];
    const float* ws1 = (const float*)d_in[16]; const float* bs1 = (const float*)d_in[17];
    const float* ws2 = (const float*)d_in[18]; const float* bs2 = (const float*)d_in[19];
    const float* wg  = (const float*)d_in[20]; const float* bg  = (const float*)d_in[21];
    const float* wh  = (const float*)d_in[22]; const float* bh  = (const float*)d_in[23];
    const float* wc1 = (const float*)d_in[24]; const float* bc1 = (const float*)d_in[25];
    const float* wc2 = (const float*)d_in[26]; const float* bc2 = (const float*)d_in[27];

    float* ws = (float*)d_ws;
    float* R1 = ws;
    float* R2 = ws + 3870720;
    float* R3 = ws + 7544832;
    float* Wg = ws + 8628864;

    ushort_t* in1p  = (ushort_t*)R1;
    ushort_t* c1out = (ushort_t*)R2;
    ushort_t* p1out = (ushort_t*)R3;
    ushort_t* c2out = (ushort_t*)R1;
    ushort_t* p2out = (ushort_t*)R2;
    ushort_t* c3out = (ushort_t*)(R2 + 775200);
    ushort_t* c4out = (ushort_t*)R1;
    ushort_t* c5out = (ushort_t*)R3;
    ushort_t* WT    = (ushort_t*)Wg;

    // ---- conv stack: v14 (2x2 waves, flattened N, merged pad/zero launches) ----
    prep1f_k<<<(BATCH * HP1 * WP1 + 255) / 256, 256, 0, stream>>>(search, exemp, in1p);
    wprep_k<<<18, 256, 0, stream>>>(aw1, WT, 11, 12, 11, 4, 3, 18, 4608, 64, nullptr, 0);
    conv_mfma14<4, false><<<dim3(1792, 1), 256, 0, stream>>>(
        in1p, WT, ab1, c1out, HP1, WP1, 4, W1, H1 * W1, BATCH * H1 * W1, 9, 12, H1, W1, 0, 64);
    pool_p_k<<<(BATCH * 64 * 51 * 39 + 255) / 256, 256, 0, stream>>>(
        c1out, p1out, 64, H1, W1, H1P, W1P, 51, 39, 2, nullptr, 0);
    wprep_k<<<150, 256, 0, stream>>>(aw2, WT, 5, 5, 5, 64, 64, 50, 38400, 192, nullptr, 0);
    conv_mfma14<1, true><<<dim3(437, 3), 256, 0, stream>>>(
        p1out, WT, ab2, c2out, 51, 39, 64, W1P, H1P * W1P, BATCH * H1P * W1P, 25, 5, H1P, W1P, 0, 192);
    // pool2 merged with c3out zero-fill (extra 1515 blocks)
    pool_p_k<<<(BATCH * 192 * 25 * 19 + 255) / 256 + 1515, 256, 0, stream>>>(
        c2out, p2out, 192, H1P, W1P, H2P, W2P, 25, 19, 1, (float4*)(R2 + 775200), 387600);
    wprep_k<<<324, 256, 0, stream>>>(aw3, WT, 3, 3, 3, 192, 192, 54, 82944, 384, nullptr, 0);
    conv_mfma14<1, true><<<dim3(104, 6), 256, 0, stream>>>(
        p2out, WT, ab3, c3out, 25, 19, 192, W2P, H2P * W2P, BATCH * H2P * W2P, 27, 3, 25, 19, 1, 384);
    // wprep4 merged with c4out zero-fill (extra 1010 blocks)
    wprep_k<<<432 + 1010, 256, 0, stream>>>(aw4, WT, 3, 3, 3, 384, 384, 108, 110592, 256,
                                            (float4*)R1, 258400);
    conv_mfma14<1, true><<<dim3(104, 4), 256, 0, stream>>>(
        c3out, WT, ab4, c4out, 25, 19, 384, W2P, H2P * W2P, BATCH * H2P * W2P, 54, 3, 25, 19, 1, 256);
    wprep_k<<<288, 256, 0, stream>>>(aw5, WT, 3, 3, 3, 256, 256, 72, 73728, 256, nullptr, 0);
    conv_mfma14<1, true><<<dim3(104, 4), 256, 0, stream>>>(
        c4out, WT, ab5, c5out, 25, 19, 256, W2P, H2P * W2P, BATCH * H2P * W2P, 36, 3, H2P, W2P, 0, 256);

    // ---- tail region layout in R1 ----
    float*    P      = R1 + 2417664;
    ushort_t* PB     = (ushort_t*)(R1 + 2800640);
    ushort_t* XfPad  = (ushort_t*)(R1 + 2992128);
    float*    xc     = R1 + 3003648;

    ushort_t* WS1T = (ushort_t*)Wg;
    ushort_t* WS2T = (ushort_t*)(Wg + 65536);
    ushort_t* WCDT = (ushort_t*)(Wg + 131072);

    // merged: gemm weight prep + pool5
    wg_pool5_k<<<224 + (BATCH * 256 * MM + 255) / 256, 256, 0, stream>>>(
        ws1, ws2, wcd, WS1T, WS2T, WCDT, c5out, P, PB, XfPad);
    float* Xf2 = P;

    float* xhat = R1 + 1024;
    float* Y1   = R1 + 23552;
    ushort_t* h1b = (ushort_t*)(R1 + 752640);
    float* Y2   = R1 + 1473536;
    float* h2   = R1 + 1838080;
    float* V1   = R1 + 2198528;
    float* Vx   = R1 + 2221056;
    float* G    = R1 + 2243584;
    float* Hh   = R1 + 2266112;
    float* A2   = R1 + 2296832;
    float* t1   = R1 + 2305024;
    float* c1   = R1 + 2338816;
    float* t2   = R1 + 2372608;
    float* V2m  = R1 + 2395136;

    // merged: xc-gemm + Y1-gemm
    gemm_pair_k<<<dim3(24, 8), 256, 0, stream>>>(XfPad, WCDT, bcd, xc, PB, WS1T, Y1);
    // merged: xhat (w/ vmax) + sh1
    xhat_sh1_k<<<120, 256, 0, stream>>>(xc, wt, bt, xhat, Y1, bs1, h1b);

    gemm_mfma3_k<0, false, true><<<dim3(22, 4), 256, 0, stream>>>(
        h1b, WS2T, nullptr, Y2, 512, TM, 16, 256, 1);
    sh2_k<<<(T_EX * 256 + 255) / 256, 256, 0, stream>>>(Y2, bs2, h2);
    v1vx_k<<<(DD * MM + 255) / 256, 256, 0, stream>>>(h2, xhat, V1, Vx);

    // merged: lin88 (g,h) + t1
    lin_t1_k<<<308, 256, 0, stream>>>(wg, bg, wh, bh, Vx, G, Hh, V1, wc1, t1);
    smsm_k<<<MM, 128, 0, stream>>>(Hh, G, A2);

    c1_k<<<(MM * 384 + 255) / 256, 256, 0, stream>>>(A2, t1, bc1, c1);
    t2_k<<<(MM * 256 + 255) / 256, 256, 0, stream>>>(c1, wc2, t2);
    v2_k<<<(MM * 256 + 255) / 256, 256, 0, stream>>>(A2, t2, bc2, V2m);

    final_k<<<1, 256, 0, stream>>>(Xf2, V2m, (float*)d_out);
}